// Round 2
// baseline (401.476 us; speedup 1.0000x reference)
//
#include <hip/hip_runtime.h>

typedef unsigned short u16;
typedef __attribute__((ext_vector_type(8))) short short8;
typedef __attribute__((ext_vector_type(4))) float f32x4;

#define S_LEN 2048
#define NH 16
#define HD 64
#define DM 1024

__device__ __forceinline__ u16 f2bf(float f) {
    union { float f; unsigned int u; } v; v.f = f;
    unsigned int u = v.u;
    unsigned int r = u + 0x7fffu + ((u >> 16) & 1u);
    return (u16)(r >> 16);
}
__device__ __forceinline__ float bf2f(u16 h) {
    union { unsigned int u; float f; } v; v.u = ((unsigned int)h) << 16;
    return v.f;
}

__device__ __forceinline__ void load_lds16(const u16* g, u16* l) {
    __builtin_amdgcn_global_load_lds((const __attribute__((address_space(1))) void*)g,
                                     (__attribute__((address_space(3))) void*)l, 16, 0, 0);
}

// ---------------- fp32 -> bf16 convert (flat) ----------------
__global__ __launch_bounds__(256) void cvt_bf16(const float* __restrict__ in, u16* __restrict__ out, int n) {
    int i = (blockIdx.x * 256 + threadIdx.x) * 4;
    if (i < n) {
        float4 v = *(const float4*)(in + i);
        ushort4 o;
        o.x = f2bf(v.x); o.y = f2bf(v.y); o.z = f2bf(v.z); o.w = f2bf(v.w);
        *(ushort4*)(out + i) = o;
    }
}

// ---------------- W [K][N] fp32 -> Wt [N][K] bf16 ----------------
__global__ __launch_bounds__(256) void transpose_w(const float* __restrict__ W, u16* __restrict__ Wt) {
    __shared__ float tile[32][33];
    int tx = threadIdx.x, ty = threadIdx.y;           // 32 x 8
    int k0 = blockIdx.y * 32, n0 = blockIdx.x * 32;
    #pragma unroll
    for (int j = 0; j < 32; j += 8)
        tile[ty + j][tx] = W[(size_t)(k0 + ty + j) * DM + n0 + tx];
    __syncthreads();
    #pragma unroll
    for (int j = 0; j < 32; j += 8)
        Wt[(size_t)(n0 + ty + j) * DM + k0 + tx] = f2bf(tile[tx][ty + j]);
}

// ---------------- 128x128 GEMM, BK=32, global_load_lds staging ----------------
// C[m][n] = sum_k A[m][k] * Bt[n][k], K = 1024.
// MODE 0: QKV fused (N=3072): n>>10 selects Q/K/V epilogue (bf16, head-major / V-transposed)
// MODE 1: fp32 flat out [M][1024]
template<int MODE>
__global__ __launch_bounds__(256) void gemm128(const u16* __restrict__ A, const u16* __restrict__ Bt,
                                               u16* __restrict__ Qh, u16* __restrict__ Kh,
                                               u16* __restrict__ Vt, float* __restrict__ Cf) {
    __shared__ u16 Al[128 * 32];
    __shared__ u16 Bl[128 * 32];
    const int K = DM;
    int tid = threadIdx.x;
    int wave = tid >> 6, lane = tid & 63, g = lane >> 4, ln = lane & 15;
    int wm = (wave >> 1) * 64, wn = (wave & 1) * 64;
    size_t m0 = (size_t)blockIdx.y * 128, n0 = (size_t)blockIdx.x * 128;

    f32x4 acc[4][4];
    #pragma unroll
    for (int i = 0; i < 4; i++)
        #pragma unroll
        for (int j = 0; j < 4; j++)
            acc[i][j] = (f32x4){0.f, 0.f, 0.f, 0.f};

    // staging: per wave 2 calls for A + 2 for B; each call = 16 rows x 64B = 1KB
    const u16* Ag = A  + (m0 + wave * 32 + (lane >> 2)) * K + (lane & 3) * 8;
    const u16* Bg = Bt + (n0 + wave * 32 + (lane >> 2)) * K + (lane & 3) * 8;
    u16* Alw = Al + wave * 1024;   // wave-uniform LDS base
    u16* Blw = Bl + wave * 1024;

    for (int k0 = 0; k0 < K; k0 += 32) {
        __syncthreads();
        #pragma unroll
        for (int c = 0; c < 2; c++) {
            load_lds16(Ag + (size_t)c * 16 * K + k0, Alw + c * 512);
            load_lds16(Bg + (size_t)c * 16 * K + k0, Blw + c * 512);
        }
        __syncthreads();
        short8 af[4], bf[4];
        #pragma unroll
        for (int i = 0; i < 4; i++) {
            af[i] = *(const short8*)&Al[(wm + i * 16 + ln) * 32 + g * 8];
            bf[i] = *(const short8*)&Bl[(wn + i * 16 + ln) * 32 + g * 8];
        }
        #pragma unroll
        for (int mi = 0; mi < 4; mi++)
            #pragma unroll
            for (int ni = 0; ni < 4; ni++)
                acc[mi][ni] = __builtin_amdgcn_mfma_f32_16x16x32_bf16(af[mi], bf[ni], acc[mi][ni], 0, 0, 0);
    }

    #pragma unroll
    for (int mi = 0; mi < 4; mi++)
        #pragma unroll
        for (int ni = 0; ni < 4; ni++)
            #pragma unroll
            for (int r = 0; r < 4; r++) {
                int m = (int)m0 + wm + mi * 16 + g * 4 + r;
                int n = (int)n0 + wn + ni * 16 + ln;
                float v = acc[mi][ni][r];
                if (MODE == 1) {
                    Cf[(size_t)m * DM + n] = v;
                } else {
                    u16 hv = f2bf(v);
                    int b = m >> 11, s = m & (S_LEN - 1);
                    int which = n >> 10, nn = n & (DM - 1);
                    int h = nn >> 6, d = nn & (HD - 1);
                    if (which == 0)
                        Qh[(((size_t)(b * NH + h) * S_LEN + s) * HD + d)] = hv;
                    else if (which == 1)
                        Kh[(((size_t)(b * NH + h) * S_LEN + s) * HD + d)] = hv;
                    else
                        Vt[(((size_t)(b * NH + h) * HD + d) * S_LEN + s)] = hv;
                }
            }
}

// ---------------- RoPE in-place on [BH][S][HD] bf16, vectorized ----------------
__global__ __launch_bounds__(256) void rope_kernel(u16* __restrict__ T) {
    int idx = blockIdx.x * 256 + threadIdx.x;   // 32*2048*4 = 262144
    int j = idx & 3;
    int s = (idx >> 2) & (S_LEN - 1);
    int bh = idx >> 13;
    size_t base = ((size_t)bh * S_LEN + s) * HD;
    short8 h1 = *(short8*)(T + base + j * 8);
    short8 h2 = *(short8*)(T + base + 32 + j * 8);
    short8 o1, o2;
    #pragma unroll
    for (int t = 0; t < 8; t++) {
        int i = j * 8 + t;
        float t1 = bf2f((u16)h1[t]);
        float t2 = bf2f((u16)h2[t]);
        float invf = exp2f(-13.287712379549449f * (float)(2 * i) * (1.0f / 64.0f));
        float fr = (float)s * invf;
        float c = __cosf(fr), sn = __sinf(fr);
        o1[t] = (short)f2bf(t1 * c - t2 * sn);
        o2[t] = (short)f2bf(t1 * sn + t2 * c);
    }
    *(short8*)(T + base + j * 8) = o1;
    *(short8*)(T + base + 32 + j * 8) = o2;
}

// ---------------- Flash attention: barrier-free, K/V direct from global ----------------
// Qh,Kh: [BH][S][HD] bf16 (rope'd), Vt: [BH][HD][S] bf16, amask: [B][S] fp32
// attn out: [B][S][DM] bf16. Block = 4 waves; each wave owns 16 q-rows independently.
__global__ __launch_bounds__(256) void flash_kernel(const u16* __restrict__ Qh, const u16* __restrict__ Kh,
                                                    const u16* __restrict__ Vt, const float* __restrict__ amask,
                                                    u16* __restrict__ attn) {
    __shared__ u16 Pl[4][16][68];   // per-wave P transpose buffer; stride 68 -> conflict-free
    int tid = threadIdx.x;
    int wave = tid >> 6, lane = tid & 63, g = lane >> 4, ln = lane & 15;
    int qtile = blockIdx.x, bh = blockIdx.y;
    int b = bh >> 4, h = bh & (NH - 1);
    int qbase = qtile * 64;
    int qrow0 = qbase + wave * 16;
    const u16* Qb = Qh + (size_t)bh * (S_LEN * HD);
    const u16* Kb = Kh + (size_t)bh * (S_LEN * HD);
    const u16* Vb = Vt + (size_t)bh * (S_LEN * HD);
    const float* am = amask + b * S_LEN;

    short8 qa0 = *(const short8*)(Qb + (size_t)(qrow0 + ln) * HD + g * 8);
    short8 qa1 = *(const short8*)(Qb + (size_t)(qrow0 + ln) * HD + 32 + g * 8);

    f32x4 O[4];
    #pragma unroll
    for (int i = 0; i < 4; i++) O[i] = (f32x4){0.f, 0.f, 0.f, 0.f};
    float m_run[4], l_run[4];
    #pragma unroll
    for (int r = 0; r < 4; r++) { m_run[r] = -1e30f; l_run[r] = 0.f; }
    const float SCL = 0.125f * 1.4426950408889634f;   // scale * log2(e)

    u16 (*Pw)[68] = Pl[wave];

    auto step = [&](int kt, bool diag) {
        int kbase = kt * 64;
        float sarr[4][4];
        #pragma unroll
        for (int n0 = 0; n0 < 4; n0++) {
            const u16* kr = Kb + (size_t)(kbase + n0 * 16 + ln) * HD;
            short8 kb0 = *(const short8*)(kr + g * 8);
            short8 kb1 = *(const short8*)(kr + 32 + g * 8);
            f32x4 sv = (f32x4){0.f, 0.f, 0.f, 0.f};
            sv = __builtin_amdgcn_mfma_f32_16x16x32_bf16(qa0, kb0, sv, 0, 0, 0);
            sv = __builtin_amdgcn_mfma_f32_16x16x32_bf16(qa1, kb1, sv, 0, 0, 0);
            float mk = (1.0f - am[kbase + n0 * 16 + ln]) * -1.0e9f;
            #pragma unroll
            for (int r = 0; r < 4; r++) {
                float s2 = sv[r] * SCL + mk;
                if (diag && (n0 * 16 + ln > wave * 16 + g * 4 + r)) s2 = -1.0e9f;
                sarr[n0][r] = s2;
            }
        }
        float mt[4];
        #pragma unroll
        for (int r = 0; r < 4; r++)
            mt[r] = fmaxf(fmaxf(sarr[0][r], sarr[1][r]), fmaxf(sarr[2][r], sarr[3][r]));
        #pragma unroll
        for (int d = 1; d < 16; d <<= 1)
            #pragma unroll
            for (int r = 0; r < 4; r++) mt[r] = fmaxf(mt[r], __shfl_xor(mt[r], d, 64));
        float alpha[4], lt[4];
        #pragma unroll
        for (int r = 0; r < 4; r++) {
            float mn = fmaxf(m_run[r], mt[r]);
            alpha[r] = exp2f(m_run[r] - mn);
            m_run[r] = mn;
            lt[r] = 0.f;
        }
        #pragma unroll
        for (int n0 = 0; n0 < 4; n0++)
            #pragma unroll
            for (int r = 0; r < 4; r++) {
                float p = exp2f(sarr[n0][r] - m_run[r]);
                sarr[n0][r] = p;
                lt[r] += p;
            }
        #pragma unroll
        for (int d = 1; d < 16; d <<= 1)
            #pragma unroll
            for (int r = 0; r < 4; r++) lt[r] += __shfl_xor(lt[r], d, 64);
        #pragma unroll
        for (int r = 0; r < 4; r++) l_run[r] = l_run[r] * alpha[r] + lt[r];
        #pragma unroll
        for (int n0 = 0; n0 < 4; n0++)
            #pragma unroll
            for (int r = 0; r < 4; r++) O[n0][r] *= alpha[r];

        // P: C-layout -> per-wave LDS -> A-layout (wave-internal, no barrier)
        #pragma unroll
        for (int n0 = 0; n0 < 4; n0++)
            #pragma unroll
            for (int r = 0; r < 4; r++)
                Pw[g * 4 + r][n0 * 16 + ln] = f2bf(sarr[n0][r]);
        short8 pa0 = *(const short8*)&Pw[ln][g * 8];
        short8 pa1 = *(const short8*)&Pw[ln][32 + g * 8];
        #pragma unroll
        for (int n0 = 0; n0 < 4; n0++) {
            const u16* vr = Vb + (size_t)(n0 * 16 + ln) * S_LEN + kbase;
            short8 vb0 = *(const short8*)(vr + g * 8);
            short8 vb1 = *(const short8*)(vr + 32 + g * 8);
            O[n0] = __builtin_amdgcn_mfma_f32_16x16x32_bf16(pa0, vb0, O[n0], 0, 0, 0);
            O[n0] = __builtin_amdgcn_mfma_f32_16x16x32_bf16(pa1, vb1, O[n0], 0, 0, 0);
        }
    };

    for (int kt = 0; kt < qtile; ++kt) step(kt, false);
    step(qtile, true);

    #pragma unroll
    for (int r = 0; r < 4; r++) {
        float inv = 1.0f / l_run[r];
        int q = qbase + wave * 16 + g * 4 + r;
        size_t base = ((size_t)b * S_LEN + q) * DM + h * HD;
        #pragma unroll
        for (int n0 = 0; n0 < 4; n0++)
            attn[base + n0 * 16 + ln] = f2bf(O[n0][r] * inv);
    }
}

extern "C" void kernel_launch(void* const* d_in, const int* in_sizes, int n_in,
                              void* d_out, int out_size, void* d_ws, size_t ws_size,
                              hipStream_t stream) {
    const float* x     = (const float*)d_in[0];
    const float* amask = (const float*)d_in[1];
    const float* Wq    = (const float*)d_in[2];
    const float* Wk    = (const float*)d_in[3];
    const float* Wv    = (const float*)d_in[4];
    const float* Wo    = (const float*)d_in[5];
    float* out = (float*)d_out;
    char* ws = (char*)d_ws;

    u16* x_bf   = (u16*)(ws);                      // 8 MB
    u16* Wqkv_t = (u16*)(ws + 8388608);            // 6 MB  [3072][1024]
    u16* Wo_t   = (u16*)(ws + 14680064);           // 2 MB
    u16* Qh     = (u16*)(ws + 16777216);           // 8 MB
    u16* Kh     = (u16*)(ws + 25165824);           // 8 MB
    u16* Vt     = (u16*)(ws + 33554432);           // 8 MB
    u16* attn   = (u16*)(ws + 41943040);           // 8 MB

    cvt_bf16<<<4096, 256, 0, stream>>>(x, x_bf, 2 * S_LEN * DM);

    dim3 tb(32, 8), tg(32, 32);
    transpose_w<<<tg, tb, 0, stream>>>(Wq, Wqkv_t);
    transpose_w<<<tg, tb, 0, stream>>>(Wk, Wqkv_t + 1048576);
    transpose_w<<<tg, tb, 0, stream>>>(Wv, Wqkv_t + 2097152);
    transpose_w<<<tg, tb, 0, stream>>>(Wo, Wo_t);

    gemm128<0><<<dim3(24, 32), 256, 0, stream>>>(x_bf, Wqkv_t, Qh, Kh, Vt, nullptr);

    rope_kernel<<<1024, 256, 0, stream>>>(Qh);
    rope_kernel<<<1024, 256, 0, stream>>>(Kh);

    flash_kernel<<<dim3(S_LEN / 64, 2 * NH), 256, 0, stream>>>(Qh, Kh, Vt, amask, attn);

    gemm128<1><<<dim3(8, 32), 256, 0, stream>>>(attn, Wo_t, nullptr, nullptr, nullptr, out);
}

// Round 3
// 331.469 us; speedup vs baseline: 1.2112x; 1.2112x over previous
//
#include <hip/hip_runtime.h>

typedef unsigned short u16;
typedef __attribute__((ext_vector_type(8))) short short8;
typedef __attribute__((ext_vector_type(4))) float f32x4;

#define S_LEN 2048
#define NH 16
#define HD 64
#define DM 1024

__device__ __forceinline__ u16 f2bf(float f) {
    union { float f; unsigned int u; } v; v.f = f;
    unsigned int u = v.u;
    unsigned int r = u + 0x7fffu + ((u >> 16) & 1u);
    return (u16)(r >> 16);
}

__device__ __forceinline__ void load_lds16(const u16* g, u16* l) {
    __builtin_amdgcn_global_load_lds((const __attribute__((address_space(1))) void*)g,
                                     (__attribute__((address_space(3))) void*)l, 16, 0, 0);
}

// ---------------- fp32 -> bf16 convert (flat) ----------------
__global__ __launch_bounds__(256) void cvt_bf16(const float* __restrict__ in, u16* __restrict__ out, int n) {
    int i = (blockIdx.x * 256 + threadIdx.x) * 4;
    if (i < n) {
        float4 v = *(const float4*)(in + i);
        ushort4 o;
        o.x = f2bf(v.x); o.y = f2bf(v.y); o.z = f2bf(v.z); o.w = f2bf(v.w);
        *(ushort4*)(out + i) = o;
    }
}

// ---------------- 4x W [K][N] fp32 -> Wt [N][K] bf16 (one launch) ----------------
__global__ __launch_bounds__(256) void transpose_w4(const float* __restrict__ W0, const float* __restrict__ W1,
                                                    const float* __restrict__ W2, const float* __restrict__ W3,
                                                    u16* __restrict__ T0, u16* __restrict__ T1,
                                                    u16* __restrict__ T2, u16* __restrict__ T3) {
    __shared__ float tile[32][33];
    int z = blockIdx.z;
    const float* W = (z == 0) ? W0 : (z == 1) ? W1 : (z == 2) ? W2 : W3;
    u16* Wt = (z == 0) ? T0 : (z == 1) ? T1 : (z == 2) ? T2 : T3;
    int tx = threadIdx.x, ty = threadIdx.y;           // 32 x 8
    int k0 = blockIdx.y * 32, n0 = blockIdx.x * 32;
    #pragma unroll
    for (int j = 0; j < 32; j += 8)
        tile[ty + j][tx] = W[(size_t)(k0 + ty + j) * DM + n0 + tx];
    __syncthreads();
    #pragma unroll
    for (int j = 0; j < 32; j += 8)
        Wt[(size_t)(n0 + ty + j) * DM + k0 + tx] = f2bf(tile[tx][ty + j]);
}

// ---------------- 128x128 GEMM, BK=32, global_load_lds staging ----------------
// C[m][n] = sum_k A[m][k] * Bt[n][k], K = 1024.
// MODE 0: QKV fused (N=3072): Q/K get RoPE fused in epilogue; V stored transposed.
// MODE 1: fp32 flat out [M][1024]
template<int MODE>
__global__ __launch_bounds__(256) void gemm128(const u16* __restrict__ A, const u16* __restrict__ Bt,
                                               u16* __restrict__ Qh, u16* __restrict__ Kh,
                                               u16* __restrict__ Vt, float* __restrict__ Cf) {
    __shared__ u16 Al[128 * 32];
    __shared__ u16 Bl[128 * 32];
    const int K = DM;
    int tid = threadIdx.x;
    int wave = tid >> 6, lane = tid & 63, g = lane >> 4, ln = lane & 15;
    int wm = (wave >> 1) * 64, wn = (wave & 1) * 64;
    size_t mb0 = (size_t)blockIdx.y * 128, nb0 = (size_t)blockIdx.x * 128;

    f32x4 acc[4][4];
    #pragma unroll
    for (int i = 0; i < 4; i++)
        #pragma unroll
        for (int j = 0; j < 4; j++)
            acc[i][j] = (f32x4){0.f, 0.f, 0.f, 0.f};

    const u16* Ag = A  + (mb0 + wave * 32 + (lane >> 2)) * K + (lane & 3) * 8;
    const u16* Bg = Bt + (nb0 + wave * 32 + (lane >> 2)) * K + (lane & 3) * 8;
    u16* Alw = Al + wave * 1024;
    u16* Blw = Bl + wave * 1024;

    for (int k0 = 0; k0 < K; k0 += 32) {
        __syncthreads();
        #pragma unroll
        for (int c = 0; c < 2; c++) {
            load_lds16(Ag + (size_t)c * 16 * K + k0, Alw + c * 512);
            load_lds16(Bg + (size_t)c * 16 * K + k0, Blw + c * 512);
        }
        __syncthreads();
        short8 af[4], bf[4];
        #pragma unroll
        for (int i = 0; i < 4; i++) {
            af[i] = *(const short8*)&Al[(wm + i * 16 + ln) * 32 + g * 8];
            bf[i] = *(const short8*)&Bl[(wn + i * 16 + ln) * 32 + g * 8];
        }
        #pragma unroll
        for (int mi = 0; mi < 4; mi++)
            #pragma unroll
            for (int ni = 0; ni < 4; ni++)
                acc[mi][ni] = __builtin_amdgcn_mfma_f32_16x16x32_bf16(af[mi], bf[ni], acc[mi][ni], 0, 0, 0);
    }

    if (MODE == 1) {
        #pragma unroll
        for (int mi = 0; mi < 4; mi++)
            #pragma unroll
            for (int ni = 0; ni < 4; ni++)
                #pragma unroll
                for (int r = 0; r < 4; r++) {
                    int m = (int)mb0 + wm + mi * 16 + g * 4 + r;
                    int n = (int)nb0 + wn + ni * 16 + ln;
                    Cf[(size_t)m * DM + n] = acc[mi][ni][r];
                }
    } else {
        int nbase = (int)nb0 + wn;              // wave-uniform
        int which = nbase >> 10;
        int h = (nbase & (DM - 1)) >> 6;
        if (which < 2) {
            u16* dst = (which == 0) ? Qh : Kh;
            // RoPE fused: i0 = ln, i1 = 16+ln; invf = 10000^(-2i/64) = exp2(-log2(1e4)/32 * i)
            float inv0 = exp2f(-0.4152408746976557f * (float)ln);
            float inv1 = exp2f(-0.4152408746976557f * (float)(16 + ln));
            #pragma unroll
            for (int mi = 0; mi < 4; mi++) {
                #pragma unroll
                for (int r = 0; r < 4; r++) {
                    int m = (int)mb0 + wm + mi * 16 + g * 4 + r;
                    int b = m >> 11, s = m & (S_LEN - 1);
                    float fs = (float)s;
                    float sn0, cs0, sn1, cs1;
                    __sincosf(fs * inv0, &sn0, &cs0);
                    __sincosf(fs * inv1, &sn1, &cs1);
                    float a0 = acc[mi][0][r], a1 = acc[mi][1][r];
                    float a2 = acc[mi][2][r], a3 = acc[mi][3][r];
                    size_t base = ((size_t)(b * NH + h) * S_LEN + s) * HD;
                    dst[base + ln]      = f2bf(a0 * cs0 - a2 * sn0);
                    dst[base + 16 + ln] = f2bf(a1 * cs1 - a3 * sn1);
                    dst[base + 32 + ln] = f2bf(a0 * sn0 + a2 * cs0);
                    dst[base + 48 + ln] = f2bf(a1 * sn1 + a3 * cs1);
                }
            }
        } else {
            #pragma unroll
            for (int mi = 0; mi < 4; mi++) {
                int m_base = (int)mb0 + wm + mi * 16 + g * 4;
                int b = m_base >> 11, s = m_base & (S_LEN - 1);
                #pragma unroll
                for (int ni = 0; ni < 4; ni++) {
                    int d = ni * 16 + ln;
                    ushort4 pk;
                    pk.x = f2bf(acc[mi][ni][0]); pk.y = f2bf(acc[mi][ni][1]);
                    pk.z = f2bf(acc[mi][ni][2]); pk.w = f2bf(acc[mi][ni][3]);
                    *(ushort4*)&Vt[((size_t)(b * NH + h) * HD + d) * S_LEN + s] = pk;
                }
            }
        }
    }
}

// ---------------- Flash attention: LDS-staged K/V, double-buffered, 1 barrier/step ----------------
// Qh,Kh: [BH][S][HD] bf16 (rope'd), Vt: [BH][HD][S] bf16, amask: [B][S] fp32
// attn out: [B][S][DM] bf16. Block = 4 waves x 2 strips of 16 q-rows = 128 q-rows/block.
__global__ __launch_bounds__(256) void flash_kernel(const u16* __restrict__ Qh, const u16* __restrict__ Kh,
                                                    const u16* __restrict__ Vt, const float* __restrict__ amask,
                                                    u16* __restrict__ attn) {
    __shared__ u16 Kl[2][64][68];
    __shared__ u16 Vl[2][64][68];
    __shared__ u16 Pl[4][32][68];
    int tid = threadIdx.x;
    int wave = tid >> 6, lane = tid & 63, g = lane >> 4, ln = lane & 15;
    int qblk = (int)gridDim.x - 1 - (int)blockIdx.x;   // heavy blocks launch first
    int bh = blockIdx.y;
    int b = bh >> 4, h = bh & (NH - 1);
    int q0 = qblk * 128 + wave * 16;                   // strip0 base; strip1 = q0 + 64
    const u16* Qb = Qh + (size_t)bh * (S_LEN * HD);
    const u16* Kb = Kh + (size_t)bh * (S_LEN * HD);
    const u16* Vb = Vt + (size_t)bh * (S_LEN * HD);
    const float* am = amask + b * S_LEN;

    short8 qa[2][2];
    qa[0][0] = *(const short8*)(Qb + (size_t)(q0 + ln) * HD + g * 8);
    qa[0][1] = *(const short8*)(Qb + (size_t)(q0 + ln) * HD + 32 + g * 8);
    qa[1][0] = *(const short8*)(Qb + (size_t)(q0 + 64 + ln) * HD + g * 8);
    qa[1][1] = *(const short8*)(Qb + (size_t)(q0 + 64 + ln) * HD + 32 + g * 8);

    f32x4 O[2][4];
    float m_run[2][4], l_run[2][4];
    #pragma unroll
    for (int s = 0; s < 2; s++)
        #pragma unroll
        for (int i = 0; i < 4; i++) {
            O[s][i] = (f32x4){0.f, 0.f, 0.f, 0.f};
            m_run[s][i] = -1e30f; l_run[s][i] = 0.f;
        }
    const float SCL = 0.125f * 1.4426950408889634f;    // scale * log2(e)

    // staging: thread t covers K row t>>2 cols (t&3)*8 + {0,32}; same for V (row = d)
    int srow = tid >> 2, sc = (tid & 3) * 8;
    const u16* Kg = Kb + (size_t)srow * HD + sc;
    const u16* Vg = Vb + (size_t)srow * S_LEN + sc;

    int T = 2 * qblk + 2;

    // prefetch tile 0 -> buf 0
    short8 pk0 = *(const short8*)(Kg);
    short8 pk1 = *(const short8*)(Kg + 32);
    short8 pv0 = *(const short8*)(Vg);
    short8 pv1 = *(const short8*)(Vg + 32);
    *(short8*)&Kl[0][srow][sc]      = pk0;
    *(short8*)&Kl[0][srow][sc + 32] = pk1;
    *(short8*)&Vl[0][srow][sc]      = pv0;
    *(short8*)&Vl[0][srow][sc + 32] = pv1;
    __syncthreads();

    for (int kt = 0; kt < T; ++kt) {
        int cur = kt & 1;
        int kbase = kt * 64;
        int knext = (kt + 1 < T) ? (kt + 1) * 64 : 0;
        // prefetch next tile into registers (consumed at end of step)
        pk0 = *(const short8*)(Kg + (size_t)knext * HD);
        pk1 = *(const short8*)(Kg + (size_t)knext * HD + 32);
        pv0 = *(const short8*)(Vg + knext);
        pv1 = *(const short8*)(Vg + knext + 32);

        // ---- QK^T for both strips (K-frags shared) ----
        float sarr[2][4][4];
        #pragma unroll
        for (int n0 = 0; n0 < 4; n0++) {
            short8 kb0 = *(const short8*)&Kl[cur][n0 * 16 + ln][g * 8];
            short8 kb1 = *(const short8*)&Kl[cur][n0 * 16 + ln][32 + g * 8];
            f32x4 sv0 = (f32x4){0.f, 0.f, 0.f, 0.f};
            f32x4 sv1 = (f32x4){0.f, 0.f, 0.f, 0.f};
            sv0 = __builtin_amdgcn_mfma_f32_16x16x32_bf16(qa[0][0], kb0, sv0, 0, 0, 0);
            sv1 = __builtin_amdgcn_mfma_f32_16x16x32_bf16(qa[1][0], kb0, sv1, 0, 0, 0);
            sv0 = __builtin_amdgcn_mfma_f32_16x16x32_bf16(qa[0][1], kb1, sv0, 0, 0, 0);
            sv1 = __builtin_amdgcn_mfma_f32_16x16x32_bf16(qa[1][1], kb1, sv1, 0, 0, 0);
            float mk = (1.0f - am[kbase + n0 * 16 + ln]) * -1.0e9f;
            int key = kbase + n0 * 16 + ln;
            bool need0 = (kt >= T - 2);   // strip0 diag/full mask on last two steps
            bool need1 = (kt == T - 1);   // strip1 diag on final step
            #pragma unroll
            for (int r = 0; r < 4; r++) {
                int qr0 = q0 + g * 4 + r;
                float v0 = sv0[r] * SCL + mk;
                float v1 = sv1[r] * SCL + mk;
                if (need0 && key > qr0) v0 = -1.0e9f;
                if (need1 && key > qr0 + 64) v1 = -1.0e9f;
                sarr[0][n0][r] = v0;
                sarr[1][n0][r] = v1;
            }
        }

        // ---- online softmax, both strips interleaved ----
        float mt[2][4], alpha[2][4], lt[2][4];
        #pragma unroll
        for (int s = 0; s < 2; s++)
            #pragma unroll
            for (int r = 0; r < 4; r++)
                mt[s][r] = fmaxf(fmaxf(sarr[s][0][r], sarr[s][1][r]), fmaxf(sarr[s][2][r], sarr[s][3][r]));
        #pragma unroll
        for (int d = 1; d < 16; d <<= 1)
            #pragma unroll
            for (int s = 0; s < 2; s++)
                #pragma unroll
                for (int r = 0; r < 4; r++) mt[s][r] = fmaxf(mt[s][r], __shfl_xor(mt[s][r], d, 64));
        #pragma unroll
        for (int s = 0; s < 2; s++)
            #pragma unroll
            for (int r = 0; r < 4; r++) {
                float mn = fmaxf(m_run[s][r], mt[s][r]);
                alpha[s][r] = exp2f(m_run[s][r] - mn);
                m_run[s][r] = mn;
                lt[s][r] = 0.f;
            }
        #pragma unroll
        for (int s = 0; s < 2; s++)
            #pragma unroll
            for (int n0 = 0; n0 < 4; n0++)
                #pragma unroll
                for (int r = 0; r < 4; r++) {
                    float p = exp2f(sarr[s][n0][r] - m_run[s][r]);
                    sarr[s][n0][r] = p;
                    lt[s][r] += p;
                }
        #pragma unroll
        for (int d = 1; d < 16; d <<= 1)
            #pragma unroll
            for (int s = 0; s < 2; s++)
                #pragma unroll
                for (int r = 0; r < 4; r++) lt[s][r] += __shfl_xor(lt[s][r], d, 64);
        #pragma unroll
        for (int s = 0; s < 2; s++)
            #pragma unroll
            for (int r = 0; r < 4; r++) {
                l_run[s][r] = l_run[s][r] * alpha[s][r] + lt[s][r];
                #pragma unroll
                for (int n0 = 0; n0 < 4; n0++) O[s][n0][r] *= alpha[s][r];
            }

        // ---- P: C-layout -> per-wave LDS -> A-layout (wave-internal sync only) ----
        #pragma unroll
        for (int s = 0; s < 2; s++)
            #pragma unroll
            for (int n0 = 0; n0 < 4; n0++)
                #pragma unroll
                for (int r = 0; r < 4; r++)
                    Pl[wave][s * 16 + g * 4 + r][n0 * 16 + ln] = f2bf(sarr[s][n0][r]);
        short8 pa00 = *(const short8*)&Pl[wave][ln][g * 8];
        short8 pa01 = *(const short8*)&Pl[wave][ln][32 + g * 8];
        short8 pa10 = *(const short8*)&Pl[wave][16 + ln][g * 8];
        short8 pa11 = *(const short8*)&Pl[wave][16 + ln][32 + g * 8];
        #pragma unroll
        for (int n0 = 0; n0 < 4; n0++) {
            short8 vb0 = *(const short8*)&Vl[cur][n0 * 16 + ln][g * 8];
            short8 vb1 = *(const short8*)&Vl[cur][n0 * 16 + ln][32 + g * 8];
            O[0][n0] = __builtin_amdgcn_mfma_f32_16x16x32_bf16(pa00, vb0, O[0][n0], 0, 0, 0);
            O[1][n0] = __builtin_amdgcn_mfma_f32_16x16x32_bf16(pa10, vb0, O[1][n0], 0, 0, 0);
            O[0][n0] = __builtin_amdgcn_mfma_f32_16x16x32_bf16(pa01, vb1, O[0][n0], 0, 0, 0);
            O[1][n0] = __builtin_amdgcn_mfma_f32_16x16x32_bf16(pa11, vb1, O[1][n0], 0, 0, 0);
        }

        // ---- stage prefetched tile into the other buffer, single barrier ----
        *(short8*)&Kl[1 - cur][srow][sc]      = pk0;
        *(short8*)&Kl[1 - cur][srow][sc + 32] = pk1;
        *(short8*)&Vl[1 - cur][srow][sc]      = pv0;
        *(short8*)&Vl[1 - cur][srow][sc + 32] = pv1;
        __syncthreads();
    }

    // ---- epilogue ----
    #pragma unroll
    for (int s = 0; s < 2; s++)
        #pragma unroll
        for (int r = 0; r < 4; r++) {
            float inv = 1.0f / l_run[s][r];
            int q = q0 + s * 64 + g * 4 + r;
            size_t base = ((size_t)b * S_LEN + q) * DM + h * HD;
            #pragma unroll
            for (int n0 = 0; n0 < 4; n0++)
                attn[base + n0 * 16 + ln] = f2bf(O[s][n0][r] * inv);
        }
}

extern "C" void kernel_launch(void* const* d_in, const int* in_sizes, int n_in,
                              void* d_out, int out_size, void* d_ws, size_t ws_size,
                              hipStream_t stream) {
    const float* x     = (const float*)d_in[0];
    const float* amask = (const float*)d_in[1];
    const float* Wq    = (const float*)d_in[2];
    const float* Wk    = (const float*)d_in[3];
    const float* Wv    = (const float*)d_in[4];
    const float* Wo    = (const float*)d_in[5];
    float* out = (float*)d_out;
    char* ws = (char*)d_ws;

    u16* x_bf   = (u16*)(ws);                      // 8 MB
    u16* Wqkv_t = (u16*)(ws + 8388608);            // 6 MB  [3072][1024]
    u16* Wo_t   = (u16*)(ws + 14680064);           // 2 MB
    u16* Qh     = (u16*)(ws + 16777216);           // 8 MB
    u16* Kh     = (u16*)(ws + 25165824);           // 8 MB
    u16* Vt     = (u16*)(ws + 33554432);           // 8 MB
    u16* attn   = (u16*)(ws + 41943040);           // 8 MB

    cvt_bf16<<<4096, 256, 0, stream>>>(x, x_bf, 2 * S_LEN * DM);

    transpose_w4<<<dim3(32, 32, 4), dim3(32, 8), 0, stream>>>(
        Wq, Wk, Wv, Wo, Wqkv_t, Wqkv_t + 1048576, Wqkv_t + 2097152, Wo_t);

    gemm128<0><<<dim3(24, 32), 256, 0, stream>>>(x_bf, Wqkv_t, Qh, Kh, Vt, nullptr);

    flash_kernel<<<dim3(S_LEN / 128, 2 * NH), 256, 0, stream>>>(Qh, Kh, Vt, amask, attn);

    gemm128<1><<<dim3(8, 32), 256, 0, stream>>>(attn, Wo_t, nullptr, nullptr, nullptr, out);
}

// Round 4
// 302.168 us; speedup vs baseline: 1.3287x; 1.0970x over previous
//
#include <hip/hip_runtime.h>

typedef unsigned short u16;
typedef __attribute__((ext_vector_type(8))) short short8;
typedef __attribute__((ext_vector_type(4))) float f32x4;

#define S_LEN 2048
#define NH 16
#define HD 64
#define DM 1024

__device__ __forceinline__ u16 f2bf(float f) {
    union { float f; unsigned int u; } v; v.f = f;
    unsigned int u = v.u;
    unsigned int r = u + 0x7fffu + ((u >> 16) & 1u);
    return (u16)(r >> 16);
}

__device__ __forceinline__ void load_lds16(const u16* g, u16* l) {
    __builtin_amdgcn_global_load_lds((const __attribute__((address_space(1))) void*)g,
                                     (__attribute__((address_space(3))) void*)l, 16, 0, 0);
}

// ---------------- fp32 -> bf16 convert (flat) ----------------
__global__ __launch_bounds__(256) void cvt_bf16(const float* __restrict__ in, u16* __restrict__ out, int n) {
    int i = (blockIdx.x * 256 + threadIdx.x) * 4;
    if (i < n) {
        float4 v = *(const float4*)(in + i);
        ushort4 o;
        o.x = f2bf(v.x); o.y = f2bf(v.y); o.z = f2bf(v.z); o.w = f2bf(v.w);
        *(ushort4*)(out + i) = o;
    }
}

// ---------------- 4x W [K][N] fp32 -> Wt [N][K] bf16 (one launch) ----------------
__global__ __launch_bounds__(256) void transpose_w4(const float* __restrict__ W0, const float* __restrict__ W1,
                                                    const float* __restrict__ W2, const float* __restrict__ W3,
                                                    u16* __restrict__ T0, u16* __restrict__ T1,
                                                    u16* __restrict__ T2, u16* __restrict__ T3) {
    __shared__ float tile[32][33];
    int z = blockIdx.z;
    const float* W = (z == 0) ? W0 : (z == 1) ? W1 : (z == 2) ? W2 : W3;
    u16* Wt = (z == 0) ? T0 : (z == 1) ? T1 : (z == 2) ? T2 : T3;
    int tx = threadIdx.x, ty = threadIdx.y;           // 32 x 8
    int k0 = blockIdx.y * 32, n0 = blockIdx.x * 32;
    #pragma unroll
    for (int j = 0; j < 32; j += 8)
        tile[ty + j][tx] = W[(size_t)(k0 + ty + j) * DM + n0 + tx];
    __syncthreads();
    #pragma unroll
    for (int j = 0; j < 32; j += 8)
        Wt[(size_t)(n0 + ty + j) * DM + k0 + tx] = f2bf(tile[tx][ty + j]);
}

// ---------------- 128x128 GEMM, BK=32, global_load_lds staging ----------------
// C[m][n] = sum_k A[m][k] * Bt[n][k], K = 1024.
// MODE 0: QKV fused (N=3072): Q/K get RoPE fused; V stored head-major [BH][S][HD].
// MODE 1: fp32 flat out [M][1024]
template<int MODE>
__global__ __launch_bounds__(256) void gemm128(const u16* __restrict__ A, const u16* __restrict__ Bt,
                                               u16* __restrict__ Qh, u16* __restrict__ Kh,
                                               u16* __restrict__ Vh, float* __restrict__ Cf) {
    __shared__ u16 Al[128 * 32];
    __shared__ u16 Bl[128 * 32];
    const int K = DM;
    int tid = threadIdx.x;
    int wave = tid >> 6, lane = tid & 63, g = lane >> 4, ln = lane & 15;
    int wm = (wave >> 1) * 64, wn = (wave & 1) * 64;
    size_t mb0 = (size_t)blockIdx.y * 128, nb0 = (size_t)blockIdx.x * 128;

    f32x4 acc[4][4];
    #pragma unroll
    for (int i = 0; i < 4; i++)
        #pragma unroll
        for (int j = 0; j < 4; j++)
            acc[i][j] = (f32x4){0.f, 0.f, 0.f, 0.f};

    const u16* Ag = A  + (mb0 + wave * 32 + (lane >> 2)) * K + (lane & 3) * 8;
    const u16* Bg = Bt + (nb0 + wave * 32 + (lane >> 2)) * K + (lane & 3) * 8;
    u16* Alw = Al + wave * 1024;
    u16* Blw = Bl + wave * 1024;

    for (int k0 = 0; k0 < K; k0 += 32) {
        __syncthreads();
        #pragma unroll
        for (int c = 0; c < 2; c++) {
            load_lds16(Ag + (size_t)c * 16 * K + k0, Alw + c * 512);
            load_lds16(Bg + (size_t)c * 16 * K + k0, Blw + c * 512);
        }
        __syncthreads();
        short8 af[4], bf[4];
        #pragma unroll
        for (int i = 0; i < 4; i++) {
            af[i] = *(const short8*)&Al[(wm + i * 16 + ln) * 32 + g * 8];
            bf[i] = *(const short8*)&Bl[(wn + i * 16 + ln) * 32 + g * 8];
        }
        #pragma unroll
        for (int mi = 0; mi < 4; mi++)
            #pragma unroll
            for (int ni = 0; ni < 4; ni++)
                acc[mi][ni] = __builtin_amdgcn_mfma_f32_16x16x32_bf16(af[mi], bf[ni], acc[mi][ni], 0, 0, 0);
    }

    if (MODE == 1) {
        #pragma unroll
        for (int mi = 0; mi < 4; mi++)
            #pragma unroll
            for (int ni = 0; ni < 4; ni++)
                #pragma unroll
                for (int r = 0; r < 4; r++) {
                    int m = (int)mb0 + wm + mi * 16 + g * 4 + r;
                    int n = (int)nb0 + wn + ni * 16 + ln;
                    Cf[(size_t)m * DM + n] = acc[mi][ni][r];
                }
    } else {
        int nbase = (int)nb0 + wn;              // wave-uniform
        int which = nbase >> 10;
        int h = (nbase & (DM - 1)) >> 6;
        if (which < 2) {
            u16* dst = (which == 0) ? Qh : Kh;
            // RoPE fused: i0 = ln, i1 = 16+ln; invf = 10000^(-2i/64)
            float inv0 = exp2f(-0.4152408746976557f * (float)ln);
            float inv1 = exp2f(-0.4152408746976557f * (float)(16 + ln));
            #pragma unroll
            for (int mi = 0; mi < 4; mi++) {
                #pragma unroll
                for (int r = 0; r < 4; r++) {
                    int m = (int)mb0 + wm + mi * 16 + g * 4 + r;
                    int b = m >> 11, s = m & (S_LEN - 1);
                    float fs = (float)s;
                    float sn0, cs0, sn1, cs1;
                    __sincosf(fs * inv0, &sn0, &cs0);
                    __sincosf(fs * inv1, &sn1, &cs1);
                    float a0 = acc[mi][0][r], a1 = acc[mi][1][r];
                    float a2 = acc[mi][2][r], a3 = acc[mi][3][r];
                    size_t base = ((size_t)(b * NH + h) * S_LEN + s) * HD;
                    dst[base + ln]      = f2bf(a0 * cs0 - a2 * sn0);
                    dst[base + 16 + ln] = f2bf(a1 * cs1 - a3 * sn1);
                    dst[base + 32 + ln] = f2bf(a0 * sn0 + a2 * cs0);
                    dst[base + 48 + ln] = f2bf(a1 * sn1 + a3 * cs1);
                }
            }
        } else {
            #pragma unroll
            for (int mi = 0; mi < 4; mi++) {
                #pragma unroll
                for (int r = 0; r < 4; r++) {
                    int m = (int)mb0 + wm + mi * 16 + g * 4 + r;
                    int b = m >> 11, s = m & (S_LEN - 1);
                    size_t base = ((size_t)(b * NH + h) * S_LEN + s) * HD;
                    #pragma unroll
                    for (int ni = 0; ni < 4; ni++)
                        Vh[base + ni * 16 + ln] = f2bf(acc[mi][ni][r]);
                }
            }
        }
    }
}

// ---------------- V transpose: [BH][S][HD] -> [BH][HD][S] ----------------
__global__ __launch_bounds__(256) void vtrans(const u16* __restrict__ Vh, u16* __restrict__ Vt) {
    __shared__ u16 t[64][70];
    int tid = threadIdx.x;
    int s0 = blockIdx.x * 64, bh = blockIdx.y;
    int r = tid >> 2, c = (tid & 3) * 8;
    const u16* src = Vh + ((size_t)bh * S_LEN + s0) * HD;
    *(short8*)&t[r][c]      = *(const short8*)(src + (size_t)r * HD + c);
    *(short8*)&t[r][c + 32] = *(const short8*)(src + (size_t)r * HD + c + 32);
    __syncthreads();
    u16* dst = Vt + ((size_t)bh * HD + r) * S_LEN + s0;
    short8 o0, o1;
    #pragma unroll
    for (int j = 0; j < 8; j++) {
        o0[j] = (short)t[c + j][r];
        o1[j] = (short)t[c + 32 + j][r];
    }
    *(short8*)(dst + c)      = o0;
    *(short8*)(dst + c + 32) = o1;
}

// ---------------- Flash attention: 64-row q-tiles, single-buffer LDS, register prefetch ----------------
// Qh,Kh: [BH][S][HD] bf16 (rope'd), Vt: [BH][HD][S] bf16, amask: [B][S] fp32
// attn out: [B][S][DM] bf16. Heavy-first: qtile = gridDim.x-1-blockIdx.x.
__global__ __launch_bounds__(256) void flash_kernel(const u16* __restrict__ Qh, const u16* __restrict__ Kh,
                                                    const u16* __restrict__ Vt, const float* __restrict__ amask,
                                                    u16* __restrict__ attn) {
    __shared__ u16 Kl[64][68];
    __shared__ u16 Vl[64][68];
    __shared__ u16 Pl[4][16][68];
    int tid = threadIdx.x;
    int wave = tid >> 6, lane = tid & 63, g = lane >> 4, ln = lane & 15;
    int qtile = (int)gridDim.x - 1 - (int)blockIdx.x;
    int bh = blockIdx.y;
    int b = bh >> 4, h = bh & (NH - 1);
    int q0 = qtile * 64 + wave * 16;
    const u16* Qb = Qh + (size_t)bh * (S_LEN * HD);
    const u16* Kb = Kh + (size_t)bh * (S_LEN * HD);
    const u16* Vb = Vt + (size_t)bh * (S_LEN * HD);
    const float* am = amask + b * S_LEN;

    short8 qa0 = *(const short8*)(Qb + (size_t)(q0 + ln) * HD + g * 8);
    short8 qa1 = *(const short8*)(Qb + (size_t)(q0 + ln) * HD + 32 + g * 8);

    f32x4 O[4];
    float m_run[4], l_run[4];
    #pragma unroll
    for (int i = 0; i < 4; i++) {
        O[i] = (f32x4){0.f, 0.f, 0.f, 0.f};
        m_run[i] = -1e30f; l_run[i] = 0.f;
    }
    const float SCL = 0.125f * 1.4426950408889634f;   // scale * log2(e)

    int srow = tid >> 2, sc = (tid & 3) * 8;
    const u16* Kg = Kb + (size_t)srow * HD + sc;
    const u16* Vg = Vb + (size_t)srow * S_LEN + sc;
    int T = qtile + 1;

    // tile 0: load to regs, stage, barrier
    short8 pk0 = *(const short8*)(Kg);
    short8 pk1 = *(const short8*)(Kg + 32);
    short8 pv0 = *(const short8*)(Vg);
    short8 pv1 = *(const short8*)(Vg + 32);
    float mcur[4], mnext[4];
    #pragma unroll
    for (int n0 = 0; n0 < 4; n0++) mcur[n0] = am[n0 * 16 + ln];
    *(short8*)&Kl[srow][sc]      = pk0;
    *(short8*)&Kl[srow][sc + 32] = pk1;
    *(short8*)&Vl[srow][sc]      = pv0;
    *(short8*)&Vl[srow][sc + 32] = pv1;
    __syncthreads();

    for (int kt = 0; kt < T; ++kt) {
        int kbase = kt * 64;
        bool more = (kt + 1 < T);
        bool diag = (kt == T - 1);
        // prefetch next tile (full compute step to cover latency)
        if (more) {
            int knext = kbase + 64;
            pk0 = *(const short8*)(Kg + (size_t)knext * HD);
            pk1 = *(const short8*)(Kg + (size_t)knext * HD + 32);
            pv0 = *(const short8*)(Vg + knext);
            pv1 = *(const short8*)(Vg + knext + 32);
            #pragma unroll
            for (int n0 = 0; n0 < 4; n0++) mnext[n0] = am[knext + n0 * 16 + ln];
        }

        // ---- QK^T ----
        float sarr[4][4];
        #pragma unroll
        for (int n0 = 0; n0 < 4; n0++) {
            short8 kb0 = *(const short8*)&Kl[n0 * 16 + ln][g * 8];
            short8 kb1 = *(const short8*)&Kl[n0 * 16 + ln][32 + g * 8];
            f32x4 sv = (f32x4){0.f, 0.f, 0.f, 0.f};
            sv = __builtin_amdgcn_mfma_f32_16x16x32_bf16(qa0, kb0, sv, 0, 0, 0);
            sv = __builtin_amdgcn_mfma_f32_16x16x32_bf16(qa1, kb1, sv, 0, 0, 0);
            float mk = (1.0f - mcur[n0]) * -1.0e9f;
            int key = kbase + n0 * 16 + ln;
            #pragma unroll
            for (int r = 0; r < 4; r++) {
                float v = sv[r] * SCL + mk;
                if (diag && (key > q0 + g * 4 + r)) v = -1.0e9f;
                sarr[n0][r] = v;
            }
        }

        // ---- online softmax ----
        float mt[4], alpha[4], lt[4];
        #pragma unroll
        for (int r = 0; r < 4; r++)
            mt[r] = fmaxf(fmaxf(sarr[0][r], sarr[1][r]), fmaxf(sarr[2][r], sarr[3][r]));
        #pragma unroll
        for (int d = 1; d < 16; d <<= 1)
            #pragma unroll
            for (int r = 0; r < 4; r++) mt[r] = fmaxf(mt[r], __shfl_xor(mt[r], d, 64));
        #pragma unroll
        for (int r = 0; r < 4; r++) {
            float mn = fmaxf(m_run[r], mt[r]);
            alpha[r] = exp2f(m_run[r] - mn);
            m_run[r] = mn;
            lt[r] = 0.f;
        }
        #pragma unroll
        for (int n0 = 0; n0 < 4; n0++)
            #pragma unroll
            for (int r = 0; r < 4; r++) {
                float p = exp2f(sarr[n0][r] - m_run[r]);
                sarr[n0][r] = p;
                lt[r] += p;
            }
        #pragma unroll
        for (int d = 1; d < 16; d <<= 1)
            #pragma unroll
            for (int r = 0; r < 4; r++) lt[r] += __shfl_xor(lt[r], d, 64);
        #pragma unroll
        for (int r = 0; r < 4; r++) {
            l_run[r] = l_run[r] * alpha[r] + lt[r];
            #pragma unroll
            for (int n0 = 0; n0 < 4; n0++) O[n0][r] *= alpha[r];
        }

        // ---- P: C-layout -> per-wave LDS -> A-layout (wave-internal sync only) ----
        #pragma unroll
        for (int n0 = 0; n0 < 4; n0++)
            #pragma unroll
            for (int r = 0; r < 4; r++)
                Pl[wave][g * 4 + r][n0 * 16 + ln] = f2bf(sarr[n0][r]);
        short8 pa0 = *(const short8*)&Pl[wave][ln][g * 8];
        short8 pa1 = *(const short8*)&Pl[wave][ln][32 + g * 8];
        #pragma unroll
        for (int n0 = 0; n0 < 4; n0++) {
            short8 vb0 = *(const short8*)&Vl[n0 * 16 + ln][g * 8];
            short8 vb1 = *(const short8*)&Vl[n0 * 16 + ln][32 + g * 8];
            O[n0] = __builtin_amdgcn_mfma_f32_16x16x32_bf16(pa0, vb0, O[n0], 0, 0, 0);
            O[n0] = __builtin_amdgcn_mfma_f32_16x16x32_bf16(pa1, vb1, O[n0], 0, 0, 0);
        }

        __syncthreads();   // all waves done reading tile kt
        if (more) {
            *(short8*)&Kl[srow][sc]      = pk0;
            *(short8*)&Kl[srow][sc + 32] = pk1;
            *(short8*)&Vl[srow][sc]      = pv0;
            *(short8*)&Vl[srow][sc + 32] = pv1;
            #pragma unroll
            for (int n0 = 0; n0 < 4; n0++) mcur[n0] = mnext[n0];
        }
        __syncthreads();   // tile kt+1 visible
    }

    // ---- epilogue ----
    #pragma unroll
    for (int r = 0; r < 4; r++) {
        float inv = 1.0f / l_run[r];
        int q = q0 + g * 4 + r;
        size_t base = ((size_t)b * S_LEN + q) * DM + h * HD;
        #pragma unroll
        for (int n0 = 0; n0 < 4; n0++)
            attn[base + n0 * 16 + ln] = f2bf(O[n0][r] * inv);
    }
}

extern "C" void kernel_launch(void* const* d_in, const int* in_sizes, int n_in,
                              void* d_out, int out_size, void* d_ws, size_t ws_size,
                              hipStream_t stream) {
    const float* x     = (const float*)d_in[0];
    const float* amask = (const float*)d_in[1];
    const float* Wq    = (const float*)d_in[2];
    const float* Wk    = (const float*)d_in[3];
    const float* Wv    = (const float*)d_in[4];
    const float* Wo    = (const float*)d_in[5];
    float* out = (float*)d_out;
    char* ws = (char*)d_ws;

    u16* x_bf   = (u16*)(ws);                      // 8 MB
    u16* Wqkv_t = (u16*)(ws + 8388608);            // 6 MB  [3072][1024]
    u16* Wo_t   = (u16*)(ws + 14680064);           // 2 MB
    u16* Qh     = (u16*)(ws + 16777216);           // 8 MB
    u16* Kh     = (u16*)(ws + 25165824);           // 8 MB
    u16* Vt     = (u16*)(ws + 33554432);           // 8 MB
    u16* Vh     = (u16*)(ws + 41943040);           // 8 MB (dead after vtrans)
    u16* attn   = (u16*)(ws + 41943040);           // 8 MB (reuses Vh slot)

    cvt_bf16<<<4096, 256, 0, stream>>>(x, x_bf, 2 * S_LEN * DM);

    transpose_w4<<<dim3(32, 32, 4), dim3(32, 8), 0, stream>>>(
        Wq, Wk, Wv, Wo, Wqkv_t, Wqkv_t + 1048576, Wqkv_t + 2097152, Wo_t);

    gemm128<0><<<dim3(24, 32), 256, 0, stream>>>(x_bf, Wqkv_t, Qh, Kh, Vh, nullptr);

    vtrans<<<dim3(32, 2 * NH), 256, 0, stream>>>(Vh, Vt);

    flash_kernel<<<dim3(S_LEN / 64, 2 * NH), 256, 0, stream>>>(Qh, Kh, Vt, amask, attn);

    gemm128<1><<<dim3(8, 32), 256, 0, stream>>>(attn, Wo_t, nullptr, nullptr, nullptr, out);
}

// Round 5
// 265.445 us; speedup vs baseline: 1.5125x; 1.1383x over previous
//
#include <hip/hip_runtime.h>

typedef unsigned short u16;
typedef __attribute__((ext_vector_type(8))) short short8;
typedef __attribute__((ext_vector_type(4))) float f32x4;

#define S_LEN 2048
#define NH 16
#define HD 64
#define DM 1024

__device__ __forceinline__ u16 f2bf(float f) {
    union { float f; unsigned int u; } v; v.f = f;
    unsigned int u = v.u;
    unsigned int r = u + 0x7fffu + ((u >> 16) & 1u);
    return (u16)(r >> 16);
}

__device__ __forceinline__ void load_lds16(const u16* g, u16* l) {
    __builtin_amdgcn_global_load_lds((const __attribute__((address_space(1))) void*)g,
                                     (__attribute__((address_space(3))) void*)l, 16, 0, 0);
}

// ---------------- fp32 -> bf16 convert (flat) ----------------
__global__ __launch_bounds__(256) void cvt_bf16(const float* __restrict__ in, u16* __restrict__ out, int n) {
    int i = (blockIdx.x * 256 + threadIdx.x) * 4;
    if (i < n) {
        float4 v = *(const float4*)(in + i);
        ushort4 o;
        o.x = f2bf(v.x); o.y = f2bf(v.y); o.z = f2bf(v.z); o.w = f2bf(v.w);
        *(ushort4*)(out + i) = o;
    }
}

// ---------------- 4x W [K][N] fp32 -> Wt [N][K] bf16 (one launch) ----------------
__global__ __launch_bounds__(256) void transpose_w4(const float* __restrict__ W0, const float* __restrict__ W1,
                                                    const float* __restrict__ W2, const float* __restrict__ W3,
                                                    u16* __restrict__ T0, u16* __restrict__ T1,
                                                    u16* __restrict__ T2, u16* __restrict__ T3) {
    __shared__ float tile[32][33];
    int z = blockIdx.z;
    const float* W = (z == 0) ? W0 : (z == 1) ? W1 : (z == 2) ? W2 : W3;
    u16* Wt = (z == 0) ? T0 : (z == 1) ? T1 : (z == 2) ? T2 : T3;
    int tx = threadIdx.x, ty = threadIdx.y;           // 32 x 8
    int k0 = blockIdx.y * 32, n0 = blockIdx.x * 32;
    #pragma unroll
    for (int j = 0; j < 32; j += 8)
        tile[ty + j][tx] = W[(size_t)(k0 + ty + j) * DM + n0 + tx];
    __syncthreads();
    #pragma unroll
    for (int j = 0; j < 32; j += 8)
        Wt[(size_t)(n0 + ty + j) * DM + k0 + tx] = f2bf(tile[tx][ty + j]);
}

// ---------------- 128x128 GEMM, BK=32, global_load_lds staging ----------------
// MODE 0: QKV fused (N=3072): Q/K get RoPE fused; V stored head-major [BH][S][HD].
// MODE 1: fp32 flat out [M][1024]
template<int MODE>
__global__ __launch_bounds__(256) void gemm128(const u16* __restrict__ A, const u16* __restrict__ Bt,
                                               u16* __restrict__ Qh, u16* __restrict__ Kh,
                                               u16* __restrict__ Vh, float* __restrict__ Cf) {
    __shared__ u16 Al[128 * 32];
    __shared__ u16 Bl[128 * 32];
    const int K = DM;
    int tid = threadIdx.x;
    int wave = tid >> 6, lane = tid & 63, g = lane >> 4, ln = lane & 15;
    int wm = (wave >> 1) * 64, wn = (wave & 1) * 64;
    size_t mb0 = (size_t)blockIdx.y * 128, nb0 = (size_t)blockIdx.x * 128;

    f32x4 acc[4][4];
    #pragma unroll
    for (int i = 0; i < 4; i++)
        #pragma unroll
        for (int j = 0; j < 4; j++)
            acc[i][j] = (f32x4){0.f, 0.f, 0.f, 0.f};

    const u16* Ag = A  + (mb0 + wave * 32 + (lane >> 2)) * K + (lane & 3) * 8;
    const u16* Bg = Bt + (nb0 + wave * 32 + (lane >> 2)) * K + (lane & 3) * 8;
    u16* Alw = Al + wave * 1024;
    u16* Blw = Bl + wave * 1024;

    for (int k0 = 0; k0 < K; k0 += 32) {
        __syncthreads();
        #pragma unroll
        for (int c = 0; c < 2; c++) {
            load_lds16(Ag + (size_t)c * 16 * K + k0, Alw + c * 512);
            load_lds16(Bg + (size_t)c * 16 * K + k0, Blw + c * 512);
        }
        __syncthreads();
        short8 af[4], bf[4];
        #pragma unroll
        for (int i = 0; i < 4; i++) {
            af[i] = *(const short8*)&Al[(wm + i * 16 + ln) * 32 + g * 8];
            bf[i] = *(const short8*)&Bl[(wn + i * 16 + ln) * 32 + g * 8];
        }
        #pragma unroll
        for (int mi = 0; mi < 4; mi++)
            #pragma unroll
            for (int ni = 0; ni < 4; ni++)
                acc[mi][ni] = __builtin_amdgcn_mfma_f32_16x16x32_bf16(af[mi], bf[ni], acc[mi][ni], 0, 0, 0);
    }

    if (MODE == 1) {
        #pragma unroll
        for (int mi = 0; mi < 4; mi++)
            #pragma unroll
            for (int ni = 0; ni < 4; ni++)
                #pragma unroll
                for (int r = 0; r < 4; r++) {
                    int m = (int)mb0 + wm + mi * 16 + g * 4 + r;
                    int n = (int)nb0 + wn + ni * 16 + ln;
                    Cf[(size_t)m * DM + n] = acc[mi][ni][r];
                }
    } else {
        int nbase = (int)nb0 + wn;              // wave-uniform
        int which = nbase >> 10;
        int h = (nbase & (DM - 1)) >> 6;
        if (which < 2) {
            u16* dst = (which == 0) ? Qh : Kh;
            float inv0 = exp2f(-0.4152408746976557f * (float)ln);
            float inv1 = exp2f(-0.4152408746976557f * (float)(16 + ln));
            #pragma unroll
            for (int mi = 0; mi < 4; mi++) {
                #pragma unroll
                for (int r = 0; r < 4; r++) {
                    int m = (int)mb0 + wm + mi * 16 + g * 4 + r;
                    int b = m >> 11, s = m & (S_LEN - 1);
                    float fs = (float)s;
                    float sn0, cs0, sn1, cs1;
                    __sincosf(fs * inv0, &sn0, &cs0);
                    __sincosf(fs * inv1, &sn1, &cs1);
                    float a0 = acc[mi][0][r], a1 = acc[mi][1][r];
                    float a2 = acc[mi][2][r], a3 = acc[mi][3][r];
                    size_t base = ((size_t)(b * NH + h) * S_LEN + s) * HD;
                    dst[base + ln]      = f2bf(a0 * cs0 - a2 * sn0);
                    dst[base + 16 + ln] = f2bf(a1 * cs1 - a3 * sn1);
                    dst[base + 32 + ln] = f2bf(a0 * sn0 + a2 * cs0);
                    dst[base + 48 + ln] = f2bf(a1 * sn1 + a3 * cs1);
                }
            }
        } else {
            #pragma unroll
            for (int mi = 0; mi < 4; mi++) {
                #pragma unroll
                for (int r = 0; r < 4; r++) {
                    int m = (int)mb0 + wm + mi * 16 + g * 4 + r;
                    int b = m >> 11, s = m & (S_LEN - 1);
                    size_t base = ((size_t)(b * NH + h) * S_LEN + s) * HD;
                    #pragma unroll
                    for (int ni = 0; ni < 4; ni++)
                        Vh[base + ni * 16 + ln] = f2bf(acc[mi][ni][r]);
                }
            }
        }
    }
}

// ---------------- V transpose: [BH][S][HD] -> [BH][HD][S] ----------------
__global__ __launch_bounds__(256) void vtrans(const u16* __restrict__ Vh, u16* __restrict__ Vt) {
    __shared__ u16 t[64][70];
    int tid = threadIdx.x;
    int s0 = blockIdx.x * 64, bh = blockIdx.y;
    int r = tid >> 2, c = (tid & 3) * 8;
    const u16* src = Vh + ((size_t)bh * S_LEN + s0) * HD;
    *(short8*)&t[r][c]      = *(const short8*)(src + (size_t)r * HD + c);
    *(short8*)&t[r][c + 32] = *(const short8*)(src + (size_t)r * HD + c + 32);
    __syncthreads();
    u16* dst = Vt + ((size_t)bh * HD + r) * S_LEN + s0;
    short8 o0, o1;
    #pragma unroll
    for (int j = 0; j < 8; j++) {
        o0[j] = (short)t[c + j][r];
        o1[j] = (short)t[c + 32 + j][r];
    }
    *(short8*)(dst + c)      = o0;
    *(short8*)(dst + c + 32) = o1;
}

// ---------------- Flash attention: round-1 structure + max-free softmax ----------------
// Qh,Kh: [BH][S][HD] bf16 (rope'd), Vt: [BH][HD][S] bf16, amask: [B][S] fp32
// attn out: [B][S][DM] bf16.
// Max-free: scores bounded (~|s|<10) so exp2 in fp32 cannot overflow; row-sum kept
// per-lane and reduced once in the epilogue -> zero cross-lane ops in the loop.
__global__ __launch_bounds__(256) void flash_kernel(const u16* __restrict__ Qh, const u16* __restrict__ Kh,
                                                    const u16* __restrict__ Vt, const float* __restrict__ amask,
                                                    u16* __restrict__ attn) {
    __shared__ u16 Kl[64][72];   // stride 72: 16B-aligned rows, uniform banking for b128
    __shared__ u16 Vl[64][72];
    __shared__ u16 Pl[4][16][68]; // stride 68: zero-conflict scalar writes (r2 evidence)
    int tid = threadIdx.x;
    int wave = tid >> 6, lane = tid & 63, g = lane >> 4, ln = lane & 15;
    int qtile = blockIdx.x, bh = blockIdx.y;
    int b = bh >> 4, h = bh & (NH - 1);
    int q0 = qtile * 64 + wave * 16;
    const u16* Qb = Qh + (size_t)bh * (S_LEN * HD);
    const u16* Kb = Kh + (size_t)bh * (S_LEN * HD);
    const u16* Vb = Vt + (size_t)bh * (S_LEN * HD);
    const float* am = amask + b * S_LEN;

    short8 qa0 = *(const short8*)(Qb + (size_t)(q0 + ln) * HD + g * 8);
    short8 qa1 = *(const short8*)(Qb + (size_t)(q0 + ln) * HD + 32 + g * 8);

    f32x4 O[4];
    float lpart[4];
    #pragma unroll
    for (int i = 0; i < 4; i++) {
        O[i] = (f32x4){0.f, 0.f, 0.f, 0.f};
        lpart[i] = 0.f;
    }
    const float SCL = 0.125f * 1.4426950408889634f;       // scale * log2(e)
    const float MSCL = -1.4426950408889634e9f;            // -1e9 * log2(e)

    int T = qtile + 1;

    for (int kt = 0; kt < T; ++kt) {
        int kbase = kt * 64;
        bool diag = (kt == T - 1);
        __syncthreads();
        #pragma unroll
        for (int p = 0; p < 2; p++) {
            int idx = tid + p * 256;
            int row = idx >> 3, c8 = (idx & 7) * 8;
            *(short8*)&Kl[row][c8] = *(const short8*)(Kb + (size_t)(kbase + row) * HD + c8);
            *(short8*)&Vl[row][c8] = *(const short8*)(Vb + (size_t)row * S_LEN + kbase + c8);
        }
        __syncthreads();

        // ---- QK^T + exp2 (no max, no shuffles) ----
        #pragma unroll
        for (int n0 = 0; n0 < 4; n0++) {
            short8 kb0 = *(const short8*)&Kl[n0 * 16 + ln][g * 8];
            short8 kb1 = *(const short8*)&Kl[n0 * 16 + ln][32 + g * 8];
            f32x4 sv = (f32x4){0.f, 0.f, 0.f, 0.f};
            sv = __builtin_amdgcn_mfma_f32_16x16x32_bf16(qa0, kb0, sv, 0, 0, 0);
            sv = __builtin_amdgcn_mfma_f32_16x16x32_bf16(qa1, kb1, sv, 0, 0, 0);
            float mk = (1.0f - am[kbase + n0 * 16 + ln]) * MSCL;
            int key = kbase + n0 * 16 + ln;
            #pragma unroll
            for (int r = 0; r < 4; r++) {
                float s2 = sv[r] * SCL + mk;
                if (diag && (key > q0 + g * 4 + r)) s2 = -1.0e9f;
                float p = exp2f(s2);
                lpart[r] += p;
                Pl[wave][g * 4 + r][n0 * 16 + ln] = f2bf(p);
            }
        }

        // ---- P: per-wave LDS -> A-layout (wave-internal sync only) ----
        short8 pa0 = *(const short8*)&Pl[wave][ln][g * 8];
        short8 pa1 = *(const short8*)&Pl[wave][ln][32 + g * 8];
        #pragma unroll
        for (int n0 = 0; n0 < 4; n0++) {
            short8 vb0 = *(const short8*)&Vl[n0 * 16 + ln][g * 8];
            short8 vb1 = *(const short8*)&Vl[n0 * 16 + ln][32 + g * 8];
            O[n0] = __builtin_amdgcn_mfma_f32_16x16x32_bf16(pa0, vb0, O[n0], 0, 0, 0);
            O[n0] = __builtin_amdgcn_mfma_f32_16x16x32_bf16(pa1, vb1, O[n0], 0, 0, 0);
        }
    }

    // ---- epilogue: reduce row-sums across the 16-lane group, normalize, store ----
    #pragma unroll
    for (int d = 1; d < 16; d <<= 1)
        #pragma unroll
        for (int r = 0; r < 4; r++) lpart[r] += __shfl_xor(lpart[r], d, 64);
    #pragma unroll
    for (int r = 0; r < 4; r++) {
        float inv = 1.0f / lpart[r];
        int q = q0 + g * 4 + r;
        size_t base = ((size_t)b * S_LEN + q) * DM + h * HD;
        #pragma unroll
        for (int n0 = 0; n0 < 4; n0++)
            attn[base + n0 * 16 + ln] = f2bf(O[n0][r] * inv);
    }
}

extern "C" void kernel_launch(void* const* d_in, const int* in_sizes, int n_in,
                              void* d_out, int out_size, void* d_ws, size_t ws_size,
                              hipStream_t stream) {
    const float* x     = (const float*)d_in[0];
    const float* amask = (const float*)d_in[1];
    const float* Wq    = (const float*)d_in[2];
    const float* Wk    = (const float*)d_in[3];
    const float* Wv    = (const float*)d_in[4];
    const float* Wo    = (const float*)d_in[5];
    float* out = (float*)d_out;
    char* ws = (char*)d_ws;

    u16* x_bf   = (u16*)(ws);                      // 8 MB
    u16* Wqkv_t = (u16*)(ws + 8388608);            // 6 MB  [3072][1024]
    u16* Wo_t   = (u16*)(ws + 14680064);           // 2 MB
    u16* Qh     = (u16*)(ws + 16777216);           // 8 MB
    u16* Kh     = (u16*)(ws + 25165824);           // 8 MB
    u16* Vt     = (u16*)(ws + 33554432);           // 8 MB
    u16* Vh     = (u16*)(ws + 41943040);           // 8 MB (dead after vtrans)
    u16* attn   = (u16*)(ws + 41943040);           // 8 MB (reuses Vh slot)

    cvt_bf16<<<4096, 256, 0, stream>>>(x, x_bf, 2 * S_LEN * DM);

    transpose_w4<<<dim3(32, 32, 4), dim3(32, 8), 0, stream>>>(
        Wq, Wk, Wv, Wo, Wqkv_t, Wqkv_t + 1048576, Wqkv_t + 2097152, Wo_t);

    gemm128<0><<<dim3(24, 32), 256, 0, stream>>>(x_bf, Wqkv_t, Qh, Kh, Vh, nullptr);

    vtrans<<<dim3(32, 2 * NH), 256, 0, stream>>>(Vh, Vt);

    flash_kernel<<<dim3(S_LEN / 64, 2 * NH), 256, 0, stream>>>(Qh, Kh, Vt, amask, attn);

    gemm128<1><<<dim3(8, 32), 256, 0, stream>>>(attn, Wo_t, nullptr, nullptr, nullptr, out);
}

// Round 6
// 259.978 us; speedup vs baseline: 1.5443x; 1.0210x over previous
//
#include <hip/hip_runtime.h>

typedef unsigned short u16;
typedef __attribute__((ext_vector_type(8))) short short8;
typedef __attribute__((ext_vector_type(4))) float f32x4;

#define S_LEN 2048
#define NH 16
#define HD 64
#define DM 1024

__device__ __forceinline__ u16 f2bf(float f) {
    union { float f; unsigned int u; } v; v.f = f;
    unsigned int u = v.u;
    unsigned int r = u + 0x7fffu + ((u >> 16) & 1u);
    return (u16)(r >> 16);
}
__device__ __forceinline__ float bf2f(u16 h) {
    union { unsigned int u; float f; } v; v.u = ((unsigned int)h) << 16;
    return v.f;
}

__device__ __forceinline__ void load_lds16(const u16* g, u16* l) {
    __builtin_amdgcn_global_load_lds((const __attribute__((address_space(1))) void*)g,
                                     (__attribute__((address_space(3))) void*)l, 16, 0, 0);
}

// ---------------- fp32 -> bf16 convert (flat) ----------------
__global__ __launch_bounds__(256) void cvt_bf16(const float* __restrict__ in, u16* __restrict__ out, int n) {
    int i = (blockIdx.x * 256 + threadIdx.x) * 4;
    if (i < n) {
        float4 v = *(const float4*)(in + i);
        ushort4 o;
        o.x = f2bf(v.x); o.y = f2bf(v.y); o.z = f2bf(v.z); o.w = f2bf(v.w);
        *(ushort4*)(out + i) = o;
    }
}

// ---------------- 4x W [K][N] fp32 -> Wt [N][K] bf16 (one launch) ----------------
__global__ __launch_bounds__(256) void transpose_w4(const float* __restrict__ W0, const float* __restrict__ W1,
                                                    const float* __restrict__ W2, const float* __restrict__ W3,
                                                    u16* __restrict__ T0, u16* __restrict__ T1,
                                                    u16* __restrict__ T2, u16* __restrict__ T3) {
    __shared__ float tile[32][33];
    int z = blockIdx.z;
    const float* W = (z == 0) ? W0 : (z == 1) ? W1 : (z == 2) ? W2 : W3;
    u16* Wt = (z == 0) ? T0 : (z == 1) ? T1 : (z == 2) ? T2 : T3;
    int tx = threadIdx.x, ty = threadIdx.y;           // 32 x 8
    int k0 = blockIdx.y * 32, n0 = blockIdx.x * 32;
    #pragma unroll
    for (int j = 0; j < 32; j += 8)
        tile[ty + j][tx] = W[(size_t)(k0 + ty + j) * DM + n0 + tx];
    __syncthreads();
    #pragma unroll
    for (int j = 0; j < 32; j += 8)
        Wt[(size_t)(n0 + ty + j) * DM + k0 + tx] = f2bf(tile[tx][ty + j]);
}

// ---------------- 128x128 GEMM, BK=32, global_load_lds staging ----------------
// MODE 0: QKV fused (N=3072): Q/K get RoPE fused; V stored head-major [BH][S][HD].
// MODE 1: fp32 flat out [M][1024]
template<int MODE>
__global__ __launch_bounds__(256) void gemm128(const u16* __restrict__ A, const u16* __restrict__ Bt,
                                               u16* __restrict__ Qh, u16* __restrict__ Kh,
                                               u16* __restrict__ Vh, float* __restrict__ Cf) {
    __shared__ u16 Al[128 * 32];
    __shared__ u16 Bl[128 * 32];
    const int K = DM;
    int tid = threadIdx.x;
    int wave = tid >> 6, lane = tid & 63, g = lane >> 4, ln = lane & 15;
    int wm = (wave >> 1) * 64, wn = (wave & 1) * 64;
    size_t mb0 = (size_t)blockIdx.y * 128, nb0 = (size_t)blockIdx.x * 128;

    f32x4 acc[4][4];
    #pragma unroll
    for (int i = 0; i < 4; i++)
        #pragma unroll
        for (int j = 0; j < 4; j++)
            acc[i][j] = (f32x4){0.f, 0.f, 0.f, 0.f};

    const u16* Ag = A  + (mb0 + wave * 32 + (lane >> 2)) * K + (lane & 3) * 8;
    const u16* Bg = Bt + (nb0 + wave * 32 + (lane >> 2)) * K + (lane & 3) * 8;
    u16* Alw = Al + wave * 1024;
    u16* Blw = Bl + wave * 1024;

    for (int k0 = 0; k0 < K; k0 += 32) {
        __syncthreads();
        #pragma unroll
        for (int c = 0; c < 2; c++) {
            load_lds16(Ag + (size_t)c * 16 * K + k0, Alw + c * 512);
            load_lds16(Bg + (size_t)c * 16 * K + k0, Blw + c * 512);
        }
        __syncthreads();
        short8 af[4], bf[4];
        #pragma unroll
        for (int i = 0; i < 4; i++) {
            af[i] = *(const short8*)&Al[(wm + i * 16 + ln) * 32 + g * 8];
            bf[i] = *(const short8*)&Bl[(wn + i * 16 + ln) * 32 + g * 8];
        }
        #pragma unroll
        for (int mi = 0; mi < 4; mi++)
            #pragma unroll
            for (int ni = 0; ni < 4; ni++)
                acc[mi][ni] = __builtin_amdgcn_mfma_f32_16x16x32_bf16(af[mi], bf[ni], acc[mi][ni], 0, 0, 0);
    }

    if (MODE == 1) {
        #pragma unroll
        for (int mi = 0; mi < 4; mi++)
            #pragma unroll
            for (int ni = 0; ni < 4; ni++)
                #pragma unroll
                for (int r = 0; r < 4; r++) {
                    int m = (int)mb0 + wm + mi * 16 + g * 4 + r;
                    int n = (int)nb0 + wn + ni * 16 + ln;
                    Cf[(size_t)m * DM + n] = acc[mi][ni][r];
                }
    } else {
        int nbase = (int)nb0 + wn;              // wave-uniform
        int which = nbase >> 10;
        int h = (nbase & (DM - 1)) >> 6;
        if (which < 2) {
            u16* dst = (which == 0) ? Qh : Kh;
            float inv0 = exp2f(-0.4152408746976557f * (float)ln);
            float inv1 = exp2f(-0.4152408746976557f * (float)(16 + ln));
            #pragma unroll
            for (int mi = 0; mi < 4; mi++) {
                #pragma unroll
                for (int r = 0; r < 4; r++) {
                    int m = (int)mb0 + wm + mi * 16 + g * 4 + r;
                    int b = m >> 11, s = m & (S_LEN - 1);
                    float fs = (float)s;
                    float sn0, cs0, sn1, cs1;
                    __sincosf(fs * inv0, &sn0, &cs0);
                    __sincosf(fs * inv1, &sn1, &cs1);
                    float a0 = acc[mi][0][r], a1 = acc[mi][1][r];
                    float a2 = acc[mi][2][r], a3 = acc[mi][3][r];
                    size_t base = ((size_t)(b * NH + h) * S_LEN + s) * HD;
                    dst[base + ln]      = f2bf(a0 * cs0 - a2 * sn0);
                    dst[base + 16 + ln] = f2bf(a1 * cs1 - a3 * sn1);
                    dst[base + 32 + ln] = f2bf(a0 * sn0 + a2 * cs0);
                    dst[base + 48 + ln] = f2bf(a1 * sn1 + a3 * cs1);
                }
            }
        } else {
            #pragma unroll
            for (int mi = 0; mi < 4; mi++) {
                #pragma unroll
                for (int r = 0; r < 4; r++) {
                    int m = (int)mb0 + wm + mi * 16 + g * 4 + r;
                    int b = m >> 11, s = m & (S_LEN - 1);
                    size_t base = ((size_t)(b * NH + h) * S_LEN + s) * HD;
                    #pragma unroll
                    for (int ni = 0; ni < 4; ni++)
                        Vh[base + ni * 16 + ln] = f2bf(acc[mi][ni][r]);
                }
            }
        }
    }
}

// ---------------- V transpose: [BH][S][HD] -> [BH][HD][S] ----------------
__global__ __launch_bounds__(256) void vtrans(const u16* __restrict__ Vh, u16* __restrict__ Vt) {
    __shared__ u16 t[64][70];
    int tid = threadIdx.x;
    int s0 = blockIdx.x * 64, bh = blockIdx.y;
    int r = tid >> 2, c = (tid & 3) * 8;
    const u16* src = Vh + ((size_t)bh * S_LEN + s0) * HD;
    *(short8*)&t[r][c]      = *(const short8*)(src + (size_t)r * HD + c);
    *(short8*)&t[r][c + 32] = *(const short8*)(src + (size_t)r * HD + c + 32);
    __syncthreads();
    u16* dst = Vt + ((size_t)bh * HD + r) * S_LEN + s0;
    short8 o0, o1;
    #pragma unroll
    for (int j = 0; j < 8; j++) {
        o0[j] = (short)t[c + j][r];
        o1[j] = (short)t[c + 32 + j][r];
    }
    *(short8*)(dst + c)      = o0;
    *(short8*)(dst + c + 32) = o1;
}

// ---------------- Flash attention, K-split=2, max-free softmax ----------------
// blockIdx.x = qtile*2 + split. split 0: tiles [0, ceil(T/2)); split 1: rest.
// Each writes UNNORMALIZED partial O (bf16, attn layout) + row-sums l (fp32).
// split 0 -> Op0 (= final attn buffer), split 1 -> Op1. Reduce pass normalizes.
__global__ __launch_bounds__(256) void flash_kernel(const u16* __restrict__ Qh, const u16* __restrict__ Kh,
                                                    const u16* __restrict__ Vt, const float* __restrict__ amask,
                                                    u16* __restrict__ Op0, u16* __restrict__ Op1,
                                                    float* __restrict__ L0, float* __restrict__ L1) {
    __shared__ u16 Kl[64][72];
    __shared__ u16 Vl[64][72];
    __shared__ u16 Pl[4][16][68];
    int tid = threadIdx.x;
    int wave = tid >> 6, lane = tid & 63, g = lane >> 4, ln = lane & 15;
    int qtile = blockIdx.x >> 1, sp = blockIdx.x & 1;
    int bh = blockIdx.y;
    int b = bh >> 4, h = bh & (NH - 1);
    int q0 = qtile * 64 + wave * 16;
    const u16* Qb = Qh + (size_t)bh * (S_LEN * HD);
    const u16* Kb = Kh + (size_t)bh * (S_LEN * HD);
    const u16* Vb = Vt + (size_t)bh * (S_LEN * HD);
    const float* am = amask + b * S_LEN;

    short8 qa0 = *(const short8*)(Qb + (size_t)(q0 + ln) * HD + g * 8);
    short8 qa1 = *(const short8*)(Qb + (size_t)(q0 + ln) * HD + 32 + g * 8);

    f32x4 O[4];
    float lpart[4];
    #pragma unroll
    for (int i = 0; i < 4; i++) {
        O[i] = (f32x4){0.f, 0.f, 0.f, 0.f};
        lpart[i] = 0.f;
    }
    const float SCL = 0.125f * 1.4426950408889634f;       // scale * log2(e)
    const float MSCL = -1.4426950408889634e9f;            // -1e9 * log2(e)

    int T = qtile + 1;
    int half = (T + 1) >> 1;
    int t0 = sp ? half : 0;
    int t1 = sp ? T : half;

    for (int kt = t0; kt < t1; ++kt) {
        int kbase = kt * 64;
        bool diag = (kt == T - 1);
        __syncthreads();
        #pragma unroll
        for (int p = 0; p < 2; p++) {
            int idx = tid + p * 256;
            int row = idx >> 3, c8 = (idx & 7) * 8;
            *(short8*)&Kl[row][c8] = *(const short8*)(Kb + (size_t)(kbase + row) * HD + c8);
            *(short8*)&Vl[row][c8] = *(const short8*)(Vb + (size_t)row * S_LEN + kbase + c8);
        }
        __syncthreads();

        // ---- QK^T + exp2 (no max, no shuffles) ----
        #pragma unroll
        for (int n0 = 0; n0 < 4; n0++) {
            short8 kb0 = *(const short8*)&Kl[n0 * 16 + ln][g * 8];
            short8 kb1 = *(const short8*)&Kl[n0 * 16 + ln][32 + g * 8];
            f32x4 sv = (f32x4){0.f, 0.f, 0.f, 0.f};
            sv = __builtin_amdgcn_mfma_f32_16x16x32_bf16(qa0, kb0, sv, 0, 0, 0);
            sv = __builtin_amdgcn_mfma_f32_16x16x32_bf16(qa1, kb1, sv, 0, 0, 0);
            float mk = (1.0f - am[kbase + n0 * 16 + ln]) * MSCL;
            int key = kbase + n0 * 16 + ln;
            #pragma unroll
            for (int r = 0; r < 4; r++) {
                float s2 = sv[r] * SCL + mk;
                if (diag && (key > q0 + g * 4 + r)) s2 = -1.0e9f;
                float p = exp2f(s2);
                lpart[r] += p;
                Pl[wave][g * 4 + r][n0 * 16 + ln] = f2bf(p);
            }
        }

        // ---- P: per-wave LDS -> A-layout (wave-internal sync only) ----
        short8 pa0 = *(const short8*)&Pl[wave][ln][g * 8];
        short8 pa1 = *(const short8*)&Pl[wave][ln][32 + g * 8];
        #pragma unroll
        for (int n0 = 0; n0 < 4; n0++) {
            short8 vb0 = *(const short8*)&Vl[n0 * 16 + ln][g * 8];
            short8 vb1 = *(const short8*)&Vl[n0 * 16 + ln][32 + g * 8];
            O[n0] = __builtin_amdgcn_mfma_f32_16x16x32_bf16(pa0, vb0, O[n0], 0, 0, 0);
            O[n0] = __builtin_amdgcn_mfma_f32_16x16x32_bf16(pa1, vb1, O[n0], 0, 0, 0);
        }
    }

    // ---- epilogue: reduce row-sums across 16-lane group, store UNNORMALIZED ----
    #pragma unroll
    for (int d = 1; d < 16; d <<= 1)
        #pragma unroll
        for (int r = 0; r < 4; r++) lpart[r] += __shfl_xor(lpart[r], d, 64);
    u16* Od = sp ? Op1 : Op0;
    float* Ld = sp ? L1 : L0;
    #pragma unroll
    for (int r = 0; r < 4; r++) {
        int q = q0 + g * 4 + r;
        if (ln == 0) Ld[(size_t)bh * S_LEN + q] = lpart[r];
        size_t base = ((size_t)b * S_LEN + q) * DM + h * HD;
        #pragma unroll
        for (int n0 = 0; n0 < 4; n0++)
            Od[base + n0 * 16 + ln] = f2bf(O[n0][r]);
    }
}

// ---------------- Reduce: attn = (Op0 + Op1) / (l0 + l1), in place over Op0 ----------------
__global__ __launch_bounds__(256) void flash_reduce(u16* __restrict__ Op0, const u16* __restrict__ Op1,
                                                    const float* __restrict__ L0, const float* __restrict__ L1) {
    int i = (blockIdx.x * 256 + threadIdx.x) * 8;   // into 4M bf16 elements [b][q][h][d]
    int h = (i >> 6) & (NH - 1);
    int q = (i >> 10) & (S_LEN - 1);
    int b = i >> 21;
    size_t li = (size_t)(b * NH + h) * S_LEN + q;
    float inv = 1.0f / (L0[li] + L1[li]);
    short8 a = *(short8*)(Op0 + i);
    short8 p = *(const short8*)(Op1 + i);
    short8 o;
    #pragma unroll
    for (int j = 0; j < 8; j++)
        o[j] = (short)f2bf((bf2f((u16)a[j]) + bf2f((u16)p[j])) * inv);
    *(short8*)(Op0 + i) = o;
}

extern "C" void kernel_launch(void* const* d_in, const int* in_sizes, int n_in,
                              void* d_out, int out_size, void* d_ws, size_t ws_size,
                              hipStream_t stream) {
    const float* x     = (const float*)d_in[0];
    const float* amask = (const float*)d_in[1];
    const float* Wq    = (const float*)d_in[2];
    const float* Wk    = (const float*)d_in[3];
    const float* Wv    = (const float*)d_in[4];
    const float* Wo    = (const float*)d_in[5];
    float* out = (float*)d_out;
    char* ws = (char*)d_ws;

    // [0,8M):    x_bf (until gemm<0>), then Op1 (flash partial, split 1)
    // [8M,14.7M): Wqkv_t (until gemm<0>), then L0/L1 (flash row sums)
    // [14M,16.7M): Wo_t (alive to the end)
    u16* x_bf   = (u16*)(ws);
    u16* Op1    = (u16*)(ws);
    u16* Wqkv_t = (u16*)(ws + 8388608);
    float* L0   = (float*)(ws + 8388608);          // 256 KB
    float* L1   = (float*)(ws + 8912896);          // 256 KB
    u16* Wo_t   = (u16*)(ws + 14680064);
    u16* Qh     = (u16*)(ws + 16777216);
    u16* Kh     = (u16*)(ws + 25165824);
    u16* Vt     = (u16*)(ws + 33554432);
    u16* Vh     = (u16*)(ws + 41943040);           // dead after vtrans
    u16* attn   = (u16*)(ws + 41943040);           // Op0 = attn buffer

    cvt_bf16<<<4096, 256, 0, stream>>>(x, x_bf, 2 * S_LEN * DM);

    transpose_w4<<<dim3(32, 32, 4), dim3(32, 8), 0, stream>>>(
        Wq, Wk, Wv, Wo, Wqkv_t, Wqkv_t + 1048576, Wqkv_t + 2097152, Wo_t);

    gemm128<0><<<dim3(24, 32), 256, 0, stream>>>(x_bf, Wqkv_t, Qh, Kh, Vh, nullptr);

    vtrans<<<dim3(32, 2 * NH), 256, 0, stream>>>(Vh, Vt);

    flash_kernel<<<dim3(2 * S_LEN / 64, 2 * NH), 256, 0, stream>>>(Qh, Kh, Vt, amask, attn, Op1, L0, L1);

    flash_reduce<<<2048, 256, 0, stream>>>(attn, Op1, L0, L1);

    gemm128<1><<<dim3(8, 32), 256, 0, stream>>>(attn, Wo_t, nullptr, nullptr, nullptr, out);
}

// Round 7
// 255.115 us; speedup vs baseline: 1.5737x; 1.0191x over previous
//
#include <hip/hip_runtime.h>

typedef unsigned short u16;
typedef __attribute__((ext_vector_type(8))) short short8;
typedef __attribute__((ext_vector_type(4))) float f32x4;

#define S_LEN 2048
#define NH 16
#define HD 64
#define DM 1024

__device__ __forceinline__ u16 f2bf(float f) {
    union { float f; unsigned int u; } v; v.f = f;
    unsigned int u = v.u;
    unsigned int r = u + 0x7fffu + ((u >> 16) & 1u);
    return (u16)(r >> 16);
}
__device__ __forceinline__ float bf2f(u16 h) {
    union { unsigned int u; float f; } v; v.u = ((unsigned int)h) << 16;
    return v.f;
}

__device__ __forceinline__ void load_lds16(const u16* g, u16* l) {
    __builtin_amdgcn_global_load_lds((const __attribute__((address_space(1))) void*)g,
                                     (__attribute__((address_space(3))) void*)l, 16, 0, 0);
}

// ---------------- fp32 -> bf16 convert (flat) ----------------
__global__ __launch_bounds__(256) void cvt_bf16(const float* __restrict__ in, u16* __restrict__ out, int n) {
    int i = (blockIdx.x * 256 + threadIdx.x) * 4;
    if (i < n) {
        float4 v = *(const float4*)(in + i);
        ushort4 o;
        o.x = f2bf(v.x); o.y = f2bf(v.y); o.z = f2bf(v.z); o.w = f2bf(v.w);
        *(ushort4*)(out + i) = o;
    }
}

// ---------------- 4x W [K][N] fp32 -> Wt [N][K] bf16 (one launch) ----------------
__global__ __launch_bounds__(256) void transpose_w4(const float* __restrict__ W0, const float* __restrict__ W1,
                                                    const float* __restrict__ W2, const float* __restrict__ W3,
                                                    u16* __restrict__ T0, u16* __restrict__ T1,
                                                    u16* __restrict__ T2, u16* __restrict__ T3) {
    __shared__ float tile[32][33];
    int z = blockIdx.z;
    const float* W = (z == 0) ? W0 : (z == 1) ? W1 : (z == 2) ? W2 : W3;
    u16* Wt = (z == 0) ? T0 : (z == 1) ? T1 : (z == 2) ? T2 : T3;
    int tx = threadIdx.x, ty = threadIdx.y;           // 32 x 8
    int k0 = blockIdx.y * 32, n0 = blockIdx.x * 32;
    #pragma unroll
    for (int j = 0; j < 32; j += 8)
        tile[ty + j][tx] = W[(size_t)(k0 + ty + j) * DM + n0 + tx];
    __syncthreads();
    #pragma unroll
    for (int j = 0; j < 32; j += 8)
        Wt[(size_t)(n0 + ty + j) * DM + k0 + tx] = f2bf(tile[tx][ty + j]);
}

// ---------------- 128x128 GEMM, BK=32, global_load_lds staging ----------------
// MODE 0: QKV fused (N=3072): Q/K get RoPE fused; V stored head-major [BH][S][HD].
// MODE 1: fp32 flat out [M][1024]
template<int MODE>
__global__ __launch_bounds__(256) void gemm128(const u16* __restrict__ A, const u16* __restrict__ Bt,
                                               u16* __restrict__ Qh, u16* __restrict__ Kh,
                                               u16* __restrict__ Vh, float* __restrict__ Cf) {
    __shared__ u16 Al[128 * 32];
    __shared__ u16 Bl[128 * 32];
    const int K = DM;
    int tid = threadIdx.x;
    int wave = tid >> 6, lane = tid & 63, g = lane >> 4, ln = lane & 15;
    int wm = (wave >> 1) * 64, wn = (wave & 1) * 64;
    size_t mb0 = (size_t)blockIdx.y * 128, nb0 = (size_t)blockIdx.x * 128;

    f32x4 acc[4][4];
    #pragma unroll
    for (int i = 0; i < 4; i++)
        #pragma unroll
        for (int j = 0; j < 4; j++)
            acc[i][j] = (f32x4){0.f, 0.f, 0.f, 0.f};

    const u16* Ag = A  + (mb0 + wave * 32 + (lane >> 2)) * K + (lane & 3) * 8;
    const u16* Bg = Bt + (nb0 + wave * 32 + (lane >> 2)) * K + (lane & 3) * 8;
    u16* Alw = Al + wave * 1024;
    u16* Blw = Bl + wave * 1024;

    for (int k0 = 0; k0 < K; k0 += 32) {
        __syncthreads();
        #pragma unroll
        for (int c = 0; c < 2; c++) {
            load_lds16(Ag + (size_t)c * 16 * K + k0, Alw + c * 512);
            load_lds16(Bg + (size_t)c * 16 * K + k0, Blw + c * 512);
        }
        __syncthreads();
        short8 af[4], bf[4];
        #pragma unroll
        for (int i = 0; i < 4; i++) {
            af[i] = *(const short8*)&Al[(wm + i * 16 + ln) * 32 + g * 8];
            bf[i] = *(const short8*)&Bl[(wn + i * 16 + ln) * 32 + g * 8];
        }
        #pragma unroll
        for (int mi = 0; mi < 4; mi++)
            #pragma unroll
            for (int ni = 0; ni < 4; ni++)
                acc[mi][ni] = __builtin_amdgcn_mfma_f32_16x16x32_bf16(af[mi], bf[ni], acc[mi][ni], 0, 0, 0);
    }

    if (MODE == 1) {
        #pragma unroll
        for (int mi = 0; mi < 4; mi++)
            #pragma unroll
            for (int ni = 0; ni < 4; ni++)
                #pragma unroll
                for (int r = 0; r < 4; r++) {
                    int m = (int)mb0 + wm + mi * 16 + g * 4 + r;
                    int n = (int)nb0 + wn + ni * 16 + ln;
                    Cf[(size_t)m * DM + n] = acc[mi][ni][r];
                }
    } else {
        int nbase = (int)nb0 + wn;              // wave-uniform
        int which = nbase >> 10;
        int h = (nbase & (DM - 1)) >> 6;
        if (which < 2) {
            u16* dst = (which == 0) ? Qh : Kh;
            float inv0 = exp2f(-0.4152408746976557f * (float)ln);
            float inv1 = exp2f(-0.4152408746976557f * (float)(16 + ln));
            #pragma unroll
            for (int mi = 0; mi < 4; mi++) {
                #pragma unroll
                for (int r = 0; r < 4; r++) {
                    int m = (int)mb0 + wm + mi * 16 + g * 4 + r;
                    int b = m >> 11, s = m & (S_LEN - 1);
                    float fs = (float)s;
                    float sn0, cs0, sn1, cs1;
                    __sincosf(fs * inv0, &sn0, &cs0);
                    __sincosf(fs * inv1, &sn1, &cs1);
                    float a0 = acc[mi][0][r], a1 = acc[mi][1][r];
                    float a2 = acc[mi][2][r], a3 = acc[mi][3][r];
                    size_t base = ((size_t)(b * NH + h) * S_LEN + s) * HD;
                    dst[base + ln]      = f2bf(a0 * cs0 - a2 * sn0);
                    dst[base + 16 + ln] = f2bf(a1 * cs1 - a3 * sn1);
                    dst[base + 32 + ln] = f2bf(a0 * sn0 + a2 * cs0);
                    dst[base + 48 + ln] = f2bf(a1 * sn1 + a3 * cs1);
                }
            }
        } else {
            #pragma unroll
            for (int mi = 0; mi < 4; mi++) {
                #pragma unroll
                for (int r = 0; r < 4; r++) {
                    int m = (int)mb0 + wm + mi * 16 + g * 4 + r;
                    int b = m >> 11, s = m & (S_LEN - 1);
                    size_t base = ((size_t)(b * NH + h) * S_LEN + s) * HD;
                    #pragma unroll
                    for (int ni = 0; ni < 4; ni++)
                        Vh[base + ni * 16 + ln] = f2bf(acc[mi][ni][r]);
                }
            }
        }
    }
}

// ---------------- V transpose: [BH][S][HD] -> [BH][HD][S] ----------------
__global__ __launch_bounds__(256) void vtrans(const u16* __restrict__ Vh, u16* __restrict__ Vt) {
    __shared__ u16 t[64][70];
    int tid = threadIdx.x;
    int s0 = blockIdx.x * 64, bh = blockIdx.y;
    int r = tid >> 2, c = (tid & 3) * 8;
    const u16* src = Vh + ((size_t)bh * S_LEN + s0) * HD;
    *(short8*)&t[r][c]      = *(const short8*)(src + (size_t)r * HD + c);
    *(short8*)&t[r][c + 32] = *(const short8*)(src + (size_t)r * HD + c + 32);
    __syncthreads();
    u16* dst = Vt + ((size_t)bh * HD + r) * S_LEN + s0;
    short8 o0, o1;
    #pragma unroll
    for (int j = 0; j < 8; j++) {
        o0[j] = (short)t[c + j][r];
        o1[j] = (short)t[c + 32 + j][r];
    }
    *(short8*)(dst + c)      = o0;
    *(short8*)(dst + c + 32) = o1;
}

// ---------------- Flash attention: 8-wave blocks (128 q-rows), K-split=2, max-free ----------------
// blockIdx.x: 0..31 -> qblk = 15 - (x>>1) (heavy first), sp = x&1.
// Each block: waves w=0..7 own q-rows qblk*128 + w*16 .. +15. K/V tile staged once,
// shared by all 8 waves. Unconditional causal mask (waves 0-3 hit diag one tile early).
__global__ __launch_bounds__(512, 8) void flash_kernel(const u16* __restrict__ Qh, const u16* __restrict__ Kh,
                                                       const u16* __restrict__ Vt, const float* __restrict__ amask,
                                                       u16* __restrict__ Op0, u16* __restrict__ Op1,
                                                       float* __restrict__ L0, float* __restrict__ L1) {
    __shared__ u16 Kl[64][72];
    __shared__ u16 Vl[64][72];
    __shared__ u16 Pl[8][16][68];
    int tid = threadIdx.x;
    int wave = tid >> 6, lane = tid & 63, g = lane >> 4, ln = lane & 15;
    int qblk = 15 - ((int)blockIdx.x >> 1);
    int sp = blockIdx.x & 1;
    int bh = blockIdx.y;
    int b = bh >> 4, h = bh & (NH - 1);
    int q0 = qblk * 128 + wave * 16;
    const u16* Qb = Qh + (size_t)bh * (S_LEN * HD);
    const u16* Kb = Kh + (size_t)bh * (S_LEN * HD);
    const u16* Vb = Vt + (size_t)bh * (S_LEN * HD);
    const float* am = amask + b * S_LEN;

    short8 qa0 = *(const short8*)(Qb + (size_t)(q0 + ln) * HD + g * 8);
    short8 qa1 = *(const short8*)(Qb + (size_t)(q0 + ln) * HD + 32 + g * 8);

    f32x4 O[4];
    float lpart[4];
    #pragma unroll
    for (int i = 0; i < 4; i++) {
        O[i] = (f32x4){0.f, 0.f, 0.f, 0.f};
        lpart[i] = 0.f;
    }
    const float SCL = 0.125f * 1.4426950408889634f;       // scale * log2(e)
    const float MSCL = -1.4426950408889634e9f;            // -1e9 * log2(e)

    int T = 2 * qblk + 2;
    int half = T >> 1;
    int t0 = sp ? half : 0;
    int t1 = sp ? T : half;

    int srow = tid >> 3, sc = (tid & 7) * 8;   // 512 threads: 1 K + 1 V b128 each

    for (int kt = t0; kt < t1; ++kt) {
        int kbase = kt * 64;
        __syncthreads();
        *(short8*)&Kl[srow][sc] = *(const short8*)(Kb + (size_t)(kbase + srow) * HD + sc);
        *(short8*)&Vl[srow][sc] = *(const short8*)(Vb + (size_t)srow * S_LEN + kbase + sc);
        __syncthreads();

        // ---- QK^T + exp2 (no max, no shuffles; causal mask unconditional) ----
        #pragma unroll
        for (int n0 = 0; n0 < 4; n0++) {
            short8 kb0 = *(const short8*)&Kl[n0 * 16 + ln][g * 8];
            short8 kb1 = *(const short8*)&Kl[n0 * 16 + ln][32 + g * 8];
            f32x4 sv = (f32x4){0.f, 0.f, 0.f, 0.f};
            sv = __builtin_amdgcn_mfma_f32_16x16x32_bf16(qa0, kb0, sv, 0, 0, 0);
            sv = __builtin_amdgcn_mfma_f32_16x16x32_bf16(qa1, kb1, sv, 0, 0, 0);
            float mk = (1.0f - am[kbase + n0 * 16 + ln]) * MSCL;
            int key = kbase + n0 * 16 + ln;
            #pragma unroll
            for (int r = 0; r < 4; r++) {
                float s2 = sv[r] * SCL + mk;
                if (key > q0 + g * 4 + r) s2 = -1.0e9f;
                float p = exp2f(s2);
                lpart[r] += p;
                Pl[wave][g * 4 + r][n0 * 16 + ln] = f2bf(p);
            }
        }

        // ---- P: per-wave LDS -> A-layout (wave-internal sync only) ----
        short8 pa0 = *(const short8*)&Pl[wave][ln][g * 8];
        short8 pa1 = *(const short8*)&Pl[wave][ln][32 + g * 8];
        #pragma unroll
        for (int n0 = 0; n0 < 4; n0++) {
            short8 vb0 = *(const short8*)&Vl[n0 * 16 + ln][g * 8];
            short8 vb1 = *(const short8*)&Vl[n0 * 16 + ln][32 + g * 8];
            O[n0] = __builtin_amdgcn_mfma_f32_16x16x32_bf16(pa0, vb0, O[n0], 0, 0, 0);
            O[n0] = __builtin_amdgcn_mfma_f32_16x16x32_bf16(pa1, vb1, O[n0], 0, 0, 0);
        }
    }

    // ---- epilogue: reduce row-sums across 16-lane group, store UNNORMALIZED ----
    #pragma unroll
    for (int d = 1; d < 16; d <<= 1)
        #pragma unroll
        for (int r = 0; r < 4; r++) lpart[r] += __shfl_xor(lpart[r], d, 64);
    u16* Od = sp ? Op1 : Op0;
    float* Ld = sp ? L1 : L0;
    #pragma unroll
    for (int r = 0; r < 4; r++) {
        int q = q0 + g * 4 + r;
        if (ln == 0) Ld[(size_t)bh * S_LEN + q] = lpart[r];
        size_t base = ((size_t)b * S_LEN + q) * DM + h * HD;
        #pragma unroll
        for (int n0 = 0; n0 < 4; n0++)
            Od[base + n0 * 16 + ln] = f2bf(O[n0][r]);
    }
}

// ---------------- Reduce: attn = (Op0 + Op1) / (l0 + l1), in place over Op0 ----------------
__global__ __launch_bounds__(256) void flash_reduce(u16* __restrict__ Op0, const u16* __restrict__ Op1,
                                                    const float* __restrict__ L0, const float* __restrict__ L1) {
    int i = (blockIdx.x * 256 + threadIdx.x) * 8;   // into 4M bf16 elements [b][q][h][d]
    int h = (i >> 6) & (NH - 1);
    int q = (i >> 10) & (S_LEN - 1);
    int b = i >> 21;
    size_t li = (size_t)(b * NH + h) * S_LEN + q;
    float inv = 1.0f / (L0[li] + L1[li]);
    short8 a = *(short8*)(Op0 + i);
    short8 p = *(const short8*)(Op1 + i);
    short8 o;
    #pragma unroll
    for (int j = 0; j < 8; j++)
        o[j] = (short)f2bf((bf2f((u16)a[j]) + bf2f((u16)p[j])) * inv);
    *(short8*)(Op0 + i) = o;
}

extern "C" void kernel_launch(void* const* d_in, const int* in_sizes, int n_in,
                              void* d_out, int out_size, void* d_ws, size_t ws_size,
                              hipStream_t stream) {
    const float* x     = (const float*)d_in[0];
    const float* amask = (const float*)d_in[1];
    const float* Wq    = (const float*)d_in[2];
    const float* Wk    = (const float*)d_in[3];
    const float* Wv    = (const float*)d_in[4];
    const float* Wo    = (const float*)d_in[5];
    float* out = (float*)d_out;
    char* ws = (char*)d_ws;

    // [0,8M):    x_bf (until gemm<0>), then Op1 (flash partial, split 1)
    // [8M,14.7M): Wqkv_t (until gemm<0>), then L0/L1 (flash row sums)
    // [14M,16.7M): Wo_t (alive to the end)
    u16* x_bf   = (u16*)(ws);
    u16* Op1    = (u16*)(ws);
    u16* Wqkv_t = (u16*)(ws + 8388608);
    float* L0   = (float*)(ws + 8388608);          // 256 KB
    float* L1   = (float*)(ws + 8912896);          // 256 KB
    u16* Wo_t   = (u16*)(ws + 14680064);
    u16* Qh     = (u16*)(ws + 16777216);
    u16* Kh     = (u16*)(ws + 25165824);
    u16* Vt     = (u16*)(ws + 33554432);
    u16* Vh     = (u16*)(ws + 41943040);           // dead after vtrans
    u16* attn   = (u16*)(ws + 41943040);           // Op0 = attn buffer

    cvt_bf16<<<4096, 256, 0, stream>>>(x, x_bf, 2 * S_LEN * DM);

    transpose_w4<<<dim3(32, 32, 4), dim3(32, 8), 0, stream>>>(
        Wq, Wk, Wv, Wo, Wqkv_t, Wqkv_t + 1048576, Wqkv_t + 2097152, Wo_t);

    gemm128<0><<<dim3(24, 32), 256, 0, stream>>>(x_bf, Wqkv_t, Qh, Kh, Vh, nullptr);

    vtrans<<<dim3(32, 2 * NH), 256, 0, stream>>>(Vh, Vt);

    flash_kernel<<<dim3(32, 2 * NH), 512, 0, stream>>>(Qh, Kh, Vt, amask, attn, Op1, L0, L1);

    flash_reduce<<<2048, 256, 0, stream>>>(attn, Op1, L0, L1);

    gemm128<1><<<dim3(8, 32), 256, 0, stream>>>(attn, Wo_t, nullptr, nullptr, nullptr, out);
}

// Round 8
// 244.490 us; speedup vs baseline: 1.6421x; 1.0435x over previous
//
#include <hip/hip_runtime.h>

typedef unsigned short u16;
typedef __attribute__((ext_vector_type(8))) short short8;
typedef __attribute__((ext_vector_type(4))) float f32x4;

#define S_LEN 2048
#define NH 16
#define HD 64
#define DM 1024

__device__ __forceinline__ u16 f2bf(float f) {
    union { float f; unsigned int u; } v; v.f = f;
    unsigned int u = v.u;
    unsigned int r = u + 0x7fffu + ((u >> 16) & 1u);
    return (u16)(r >> 16);
}
__device__ __forceinline__ float bf2f(u16 h) {
    union { unsigned int u; float f; } v; v.u = ((unsigned int)h) << 16;
    return v.f;
}

__device__ __forceinline__ void load_lds16(const u16* g, u16* l) {
    __builtin_amdgcn_global_load_lds((const __attribute__((address_space(1))) void*)g,
                                     (__attribute__((address_space(3))) void*)l, 16, 0, 0);
}

// ---------------- fp32 -> bf16 convert (flat) ----------------
__global__ __launch_bounds__(256) void cvt_bf16(const float* __restrict__ in, u16* __restrict__ out, int n) {
    int i = (blockIdx.x * 256 + threadIdx.x) * 4;
    if (i < n) {
        float4 v = *(const float4*)(in + i);
        ushort4 o;
        o.x = f2bf(v.x); o.y = f2bf(v.y); o.z = f2bf(v.z); o.w = f2bf(v.w);
        *(ushort4*)(out + i) = o;
    }
}

// ---------------- 4x W [K][N] fp32 -> Wt [N][K] bf16 (one launch) ----------------
__global__ __launch_bounds__(256) void transpose_w4(const float* __restrict__ W0, const float* __restrict__ W1,
                                                    const float* __restrict__ W2, const float* __restrict__ W3,
                                                    u16* __restrict__ T0, u16* __restrict__ T1,
                                                    u16* __restrict__ T2, u16* __restrict__ T3) {
    __shared__ float tile[32][33];
    int z = blockIdx.z;
    const float* W = (z == 0) ? W0 : (z == 1) ? W1 : (z == 2) ? W2 : W3;
    u16* Wt = (z == 0) ? T0 : (z == 1) ? T1 : (z == 2) ? T2 : T3;
    int tx = threadIdx.x, ty = threadIdx.y;           // 32 x 8
    int k0 = blockIdx.y * 32, n0 = blockIdx.x * 32;
    #pragma unroll
    for (int j = 0; j < 32; j += 8)
        tile[ty + j][tx] = W[(size_t)(k0 + ty + j) * DM + n0 + tx];
    __syncthreads();
    #pragma unroll
    for (int j = 0; j < 32; j += 8)
        Wt[(size_t)(n0 + ty + j) * DM + k0 + tx] = f2bf(tile[tx][ty + j]);
}

// ---------------- 128x128 GEMM, BK=32, global_load_lds staging ----------------
// MODE 0: QKV fused (N=3072): Q/K get RoPE fused; V stored head-major [BH][S][HD].
// MODE 1: fp32 flat out [M][1024]
template<int MODE>
__global__ __launch_bounds__(256) void gemm128(const u16* __restrict__ A, const u16* __restrict__ Bt,
                                               u16* __restrict__ Qh, u16* __restrict__ Kh,
                                               u16* __restrict__ Vh, float* __restrict__ Cf) {
    __shared__ u16 Al[128 * 32];
    __shared__ u16 Bl[128 * 32];
    const int K = DM;
    int tid = threadIdx.x;
    int wave = tid >> 6, lane = tid & 63, g = lane >> 4, ln = lane & 15;
    int wm = (wave >> 1) * 64, wn = (wave & 1) * 64;
    size_t mb0 = (size_t)blockIdx.y * 128, nb0 = (size_t)blockIdx.x * 128;

    f32x4 acc[4][4];
    #pragma unroll
    for (int i = 0; i < 4; i++)
        #pragma unroll
        for (int j = 0; j < 4; j++)
            acc[i][j] = (f32x4){0.f, 0.f, 0.f, 0.f};

    const u16* Ag = A  + (mb0 + wave * 32 + (lane >> 2)) * K + (lane & 3) * 8;
    const u16* Bg = Bt + (nb0 + wave * 32 + (lane >> 2)) * K + (lane & 3) * 8;
    u16* Alw = Al + wave * 1024;
    u16* Blw = Bl + wave * 1024;

    for (int k0 = 0; k0 < K; k0 += 32) {
        __syncthreads();
        #pragma unroll
        for (int c = 0; c < 2; c++) {
            load_lds16(Ag + (size_t)c * 16 * K + k0, Alw + c * 512);
            load_lds16(Bg + (size_t)c * 16 * K + k0, Blw + c * 512);
        }
        __syncthreads();
        short8 af[4], bf[4];
        #pragma unroll
        for (int i = 0; i < 4; i++) {
            af[i] = *(const short8*)&Al[(wm + i * 16 + ln) * 32 + g * 8];
            bf[i] = *(const short8*)&Bl[(wn + i * 16 + ln) * 32 + g * 8];
        }
        #pragma unroll
        for (int mi = 0; mi < 4; mi++)
            #pragma unroll
            for (int ni = 0; ni < 4; ni++)
                acc[mi][ni] = __builtin_amdgcn_mfma_f32_16x16x32_bf16(af[mi], bf[ni], acc[mi][ni], 0, 0, 0);
    }

    if (MODE == 1) {
        #pragma unroll
        for (int mi = 0; mi < 4; mi++)
            #pragma unroll
            for (int ni = 0; ni < 4; ni++)
                #pragma unroll
                for (int r = 0; r < 4; r++) {
                    int m = (int)mb0 + wm + mi * 16 + g * 4 + r;
                    int n = (int)nb0 + wn + ni * 16 + ln;
                    Cf[(size_t)m * DM + n] = acc[mi][ni][r];
                }
    } else {
        int nbase = (int)nb0 + wn;              // wave-uniform
        int which = nbase >> 10;
        int h = (nbase & (DM - 1)) >> 6;
        if (which < 2) {
            u16* dst = (which == 0) ? Qh : Kh;
            float inv0 = exp2f(-0.4152408746976557f * (float)ln);
            float inv1 = exp2f(-0.4152408746976557f * (float)(16 + ln));
            #pragma unroll
            for (int mi = 0; mi < 4; mi++) {
                #pragma unroll
                for (int r = 0; r < 4; r++) {
                    int m = (int)mb0 + wm + mi * 16 + g * 4 + r;
                    int b = m >> 11, s = m & (S_LEN - 1);
                    float fs = (float)s;
                    float sn0, cs0, sn1, cs1;
                    __sincosf(fs * inv0, &sn0, &cs0);
                    __sincosf(fs * inv1, &sn1, &cs1);
                    float a0 = acc[mi][0][r], a1 = acc[mi][1][r];
                    float a2 = acc[mi][2][r], a3 = acc[mi][3][r];
                    size_t base = ((size_t)(b * NH + h) * S_LEN + s) * HD;
                    dst[base + ln]      = f2bf(a0 * cs0 - a2 * sn0);
                    dst[base + 16 + ln] = f2bf(a1 * cs1 - a3 * sn1);
                    dst[base + 32 + ln] = f2bf(a0 * sn0 + a2 * cs0);
                    dst[base + 48 + ln] = f2bf(a1 * sn1 + a3 * cs1);
                }
            }
        } else {
            #pragma unroll
            for (int mi = 0; mi < 4; mi++) {
                #pragma unroll
                for (int r = 0; r < 4; r++) {
                    int m = (int)mb0 + wm + mi * 16 + g * 4 + r;
                    int b = m >> 11, s = m & (S_LEN - 1);
                    size_t base = ((size_t)(b * NH + h) * S_LEN + s) * HD;
                    #pragma unroll
                    for (int ni = 0; ni < 4; ni++)
                        Vh[base + ni * 16 + ln] = f2bf(acc[mi][ni][r]);
                }
            }
        }
    }
}

// ---------------- V transpose: [BH][S][HD] -> [BH][HD][S] ----------------
__global__ __launch_bounds__(256) void vtrans(const u16* __restrict__ Vh, u16* __restrict__ Vt) {
    __shared__ u16 t[64][70];
    int tid = threadIdx.x;
    int s0 = blockIdx.x * 64, bh = blockIdx.y;
    int r = tid >> 2, c = (tid & 3) * 8;
    const u16* src = Vh + ((size_t)bh * S_LEN + s0) * HD;
    *(short8*)&t[r][c]      = *(const short8*)(src + (size_t)r * HD + c);
    *(short8*)&t[r][c + 32] = *(const short8*)(src + (size_t)r * HD + c + 32);
    __syncthreads();
    u16* dst = Vt + ((size_t)bh * HD + r) * S_LEN + s0;
    short8 o0, o1;
    #pragma unroll
    for (int j = 0; j < 8; j++) {
        o0[j] = (short)t[c + j][r];
        o1[j] = (short)t[c + 32 + j][r];
    }
    *(short8*)(dst + c)      = o0;
    *(short8*)(dst + c + 32) = o1;
}

// ---------------- Flash attention: 8-wave blocks, K-split=4 round-robin, max-free ----------------
// blockIdx.x: 0..63 -> qblk = 15 - (x>>2) (heavy first), sp = x&3.
// Split sp processes tiles {sp, sp+4, sp+8, ...} < T (T = 2*qblk+2). Partials are
// unnormalized O (bf16, attn layout) + row-sums L (fp32); reduce pass combines 4.
__global__ __launch_bounds__(512, 8) void flash_kernel(const u16* __restrict__ Qh, const u16* __restrict__ Kh,
                                                       const u16* __restrict__ Vt, const float* __restrict__ amask,
                                                       u16* __restrict__ Op0, u16* __restrict__ Op1,
                                                       u16* __restrict__ Op2, u16* __restrict__ Op3,
                                                       float* __restrict__ L0, float* __restrict__ L1,
                                                       float* __restrict__ L2, float* __restrict__ L3) {
    __shared__ u16 Kl[64][72];
    __shared__ u16 Vl[64][72];
    __shared__ u16 Pl[8][16][68];
    int tid = threadIdx.x;
    int wave = tid >> 6, lane = tid & 63, g = lane >> 4, ln = lane & 15;
    int qblk = 15 - ((int)blockIdx.x >> 2);
    int sp = blockIdx.x & 3;
    int bh = blockIdx.y;
    int b = bh >> 4, h = bh & (NH - 1);
    int q0 = qblk * 128 + wave * 16;
    const u16* Qb = Qh + (size_t)bh * (S_LEN * HD);
    const u16* Kb = Kh + (size_t)bh * (S_LEN * HD);
    const u16* Vb = Vt + (size_t)bh * (S_LEN * HD);
    const float* am = amask + b * S_LEN;

    short8 qa0 = *(const short8*)(Qb + (size_t)(q0 + ln) * HD + g * 8);
    short8 qa1 = *(const short8*)(Qb + (size_t)(q0 + ln) * HD + 32 + g * 8);

    f32x4 O[4];
    float lpart[4];
    #pragma unroll
    for (int i = 0; i < 4; i++) {
        O[i] = (f32x4){0.f, 0.f, 0.f, 0.f};
        lpart[i] = 0.f;
    }
    const float SCL = 0.125f * 1.4426950408889634f;       // scale * log2(e)
    const float MSCL = -1.4426950408889634e9f;            // -1e9 * log2(e)

    int T = 2 * qblk + 2;
    int srow = tid >> 3, sc = (tid & 7) * 8;   // 512 threads: 1 K + 1 V b128 each

    for (int kt = sp; kt < T; kt += 4) {
        int kbase = kt * 64;
        __syncthreads();
        *(short8*)&Kl[srow][sc] = *(const short8*)(Kb + (size_t)(kbase + srow) * HD + sc);
        *(short8*)&Vl[srow][sc] = *(const short8*)(Vb + (size_t)srow * S_LEN + kbase + sc);
        __syncthreads();

        bool needmask = (kbase + 63 > q0);     // wave-uniform causal guard

        // ---- QK^T + exp2 (no max, no shuffles) ----
        #pragma unroll
        for (int n0 = 0; n0 < 4; n0++) {
            short8 kb0 = *(const short8*)&Kl[n0 * 16 + ln][g * 8];
            short8 kb1 = *(const short8*)&Kl[n0 * 16 + ln][32 + g * 8];
            f32x4 sv = (f32x4){0.f, 0.f, 0.f, 0.f};
            sv = __builtin_amdgcn_mfma_f32_16x16x32_bf16(qa0, kb0, sv, 0, 0, 0);
            sv = __builtin_amdgcn_mfma_f32_16x16x32_bf16(qa1, kb1, sv, 0, 0, 0);
            float mk = (1.0f - am[kbase + n0 * 16 + ln]) * MSCL;
            int key = kbase + n0 * 16 + ln;
            if (needmask) {
                #pragma unroll
                for (int r = 0; r < 4; r++) {
                    float s2 = sv[r] * SCL + mk;
                    if (key > q0 + g * 4 + r) s2 = -1.0e9f;
                    float p = exp2f(s2);
                    lpart[r] += p;
                    Pl[wave][g * 4 + r][n0 * 16 + ln] = f2bf(p);
                }
            } else {
                #pragma unroll
                for (int r = 0; r < 4; r++) {
                    float p = exp2f(sv[r] * SCL + mk);
                    lpart[r] += p;
                    Pl[wave][g * 4 + r][n0 * 16 + ln] = f2bf(p);
                }
            }
        }

        // ---- P: per-wave LDS -> A-layout (wave-internal sync only) ----
        short8 pa0 = *(const short8*)&Pl[wave][ln][g * 8];
        short8 pa1 = *(const short8*)&Pl[wave][ln][32 + g * 8];
        #pragma unroll
        for (int n0 = 0; n0 < 4; n0++) {
            short8 vb0 = *(const short8*)&Vl[n0 * 16 + ln][g * 8];
            short8 vb1 = *(const short8*)&Vl[n0 * 16 + ln][32 + g * 8];
            O[n0] = __builtin_amdgcn_mfma_f32_16x16x32_bf16(pa0, vb0, O[n0], 0, 0, 0);
            O[n0] = __builtin_amdgcn_mfma_f32_16x16x32_bf16(pa1, vb1, O[n0], 0, 0, 0);
        }
    }

    // ---- epilogue: reduce row-sums across 16-lane group, store UNNORMALIZED ----
    #pragma unroll
    for (int d = 1; d < 16; d <<= 1)
        #pragma unroll
        for (int r = 0; r < 4; r++) lpart[r] += __shfl_xor(lpart[r], d, 64);
    u16* Od = (sp == 0) ? Op0 : (sp == 1) ? Op1 : (sp == 2) ? Op2 : Op3;
    float* Ld = (sp == 0) ? L0 : (sp == 1) ? L1 : (sp == 2) ? L2 : L3;
    #pragma unroll
    for (int r = 0; r < 4; r++) {
        int q = q0 + g * 4 + r;
        if (ln == 0) Ld[(size_t)bh * S_LEN + q] = lpart[r];
        size_t base = ((size_t)b * S_LEN + q) * DM + h * HD;
        #pragma unroll
        for (int n0 = 0; n0 < 4; n0++)
            Od[base + n0 * 16 + ln] = f2bf(O[n0][r]);
    }
}

// ---------------- Reduce: attn = (Op0+Op1+Op2+Op3) / (l0+l1+l2+l3), in place over Op0 ----------------
__global__ __launch_bounds__(256) void flash_reduce(u16* __restrict__ Op0, const u16* __restrict__ Op1,
                                                    const u16* __restrict__ Op2, const u16* __restrict__ Op3,
                                                    const float* __restrict__ L0, const float* __restrict__ L1,
                                                    const float* __restrict__ L2, const float* __restrict__ L3) {
    int i = (blockIdx.x * 256 + threadIdx.x) * 8;   // into 4M bf16 elements [b][q][h][d]
    int h = (i >> 6) & (NH - 1);
    int q = (i >> 10) & (S_LEN - 1);
    int b = i >> 21;
    size_t li = (size_t)(b * NH + h) * S_LEN + q;
    float inv = 1.0f / (L0[li] + L1[li] + L2[li] + L3[li]);
    short8 a0 = *(short8*)(Op0 + i);
    short8 a1 = *(const short8*)(Op1 + i);
    short8 a2 = *(const short8*)(Op2 + i);
    short8 a3 = *(const short8*)(Op3 + i);
    short8 o;
    #pragma unroll
    for (int j = 0; j < 8; j++)
        o[j] = (short)f2bf((bf2f((u16)a0[j]) + bf2f((u16)a1[j]) +
                            bf2f((u16)a2[j]) + bf2f((u16)a3[j])) * inv);
    *(short8*)(Op0 + i) = o;
}

extern "C" void kernel_launch(void* const* d_in, const int* in_sizes, int n_in,
                              void* d_out, int out_size, void* d_ws, size_t ws_size,
                              hipStream_t stream) {
    const float* x     = (const float*)d_in[0];
    const float* amask = (const float*)d_in[1];
    const float* Wq    = (const float*)d_in[2];
    const float* Wk    = (const float*)d_in[3];
    const float* Wv    = (const float*)d_in[4];
    const float* Wo    = (const float*)d_in[5];
    float* out = (float*)d_out;
    char* ws = (char*)d_ws;

    // [0,8M):    x_bf (until gemm<0>), then Op1 (flash partial, split 1)
    // [8M,9M):   L0..L3 (flash row sums; region dead after gemm<0>)
    // [8M,14.7M): Wqkv_t (until gemm<0>)
    // [14M,16.7M): Wo_t (alive to the end)
    // Op2/Op3 live in d_out (16MB fp32, written only by the final gemm).
    u16* x_bf   = (u16*)(ws);
    u16* Op1    = (u16*)(ws);
    u16* Wqkv_t = (u16*)(ws + 8388608);
    float* L0   = (float*)(ws + 8388608);
    float* L1   = (float*)(ws + 8650752);
    float* L2   = (float*)(ws + 8912896);
    float* L3   = (float*)(ws + 9175040);
    u16* Wo_t   = (u16*)(ws + 14680064);
    u16* Qh     = (u16*)(ws + 16777216);
    u16* Kh     = (u16*)(ws + 25165824);
    u16* Vt     = (u16*)(ws + 33554432);
    u16* Vh     = (u16*)(ws + 41943040);           // dead after vtrans
    u16* attn   = (u16*)(ws + 41943040);           // Op0 = attn buffer
    u16* Op2    = (u16*)d_out;
    u16* Op3    = (u16*)d_out + 4194304;

    cvt_bf16<<<4096, 256, 0, stream>>>(x, x_bf, 2 * S_LEN * DM);

    transpose_w4<<<dim3(32, 32, 4), dim3(32, 8), 0, stream>>>(
        Wq, Wk, Wv, Wo, Wqkv_t, Wqkv_t + 1048576, Wqkv_t + 2097152, Wo_t);

    gemm128<0><<<dim3(24, 32), 256, 0, stream>>>(x_bf, Wqkv_t, Qh, Kh, Vh, nullptr);

    vtrans<<<dim3(32, 2 * NH), 256, 0, stream>>>(Vh, Vt);

    flash_kernel<<<dim3(64, 2 * NH), 512, 0, stream>>>(Qh, Kh, Vt, amask,
                                                       attn, Op1, Op2, Op3, L0, L1, L2, L3);

    flash_reduce<<<2048, 256, 0, stream>>>(attn, Op1, Op2, Op3, L0, L1, L2, L3);

    gemm128<1><<<dim3(8, 32), 256, 0, stream>>>(attn, Wo_t, nullptr, nullptr, nullptr, out);
}

// Round 9
// 242.714 us; speedup vs baseline: 1.6541x; 1.0073x over previous
//
#include <hip/hip_runtime.h>

typedef unsigned short u16;
typedef unsigned int u32;
typedef __attribute__((ext_vector_type(8))) short short8;
typedef __attribute__((ext_vector_type(4))) short s4v;
typedef __attribute__((ext_vector_type(4))) float f32x4;

#define S_LEN 2048
#define NH 16
#define HD 64
#define DM 1024

#if __has_builtin(__builtin_amdgcn_mfma_f32_16x16x16_bf16)
#define MFMA_K16(a, b, c) __builtin_amdgcn_mfma_f32_16x16x16_bf16(a, b, c, 0, 0, 0)
#else
#define MFMA_K16(a, b, c) __builtin_amdgcn_mfma_f32_16x16x16bf16_1k(a, b, c, 0, 0, 0)
#endif

__device__ __forceinline__ u16 f2bf(float f) {
    union { float f; u32 u; } v; v.f = f;
    u32 u = v.u;
    u32 r = u + 0x7fffu + ((u >> 16) & 1u);
    return (u16)(r >> 16);
}
__device__ __forceinline__ float bf2f(u16 h) {
    union { u32 u; float f; } v; v.u = ((u32)h) << 16;
    return v.f;
}

__device__ __forceinline__ void load_lds16(const u16* g, u16* l) {
    __builtin_amdgcn_global_load_lds((const __attribute__((address_space(1))) void*)g,
                                     (__attribute__((address_space(3))) void*)l, 16, 0, 0);
}

// ---------------- fp32 -> bf16 convert (flat) ----------------
__global__ __launch_bounds__(256) void cvt_bf16(const float* __restrict__ in, u16* __restrict__ out, int n) {
    int i = (blockIdx.x * 256 + threadIdx.x) * 4;
    if (i < n) {
        float4 v = *(const float4*)(in + i);
        ushort4 o;
        o.x = f2bf(v.x); o.y = f2bf(v.y); o.z = f2bf(v.z); o.w = f2bf(v.w);
        *(ushort4*)(out + i) = o;
    }
}

// ---------------- 4x W [K][N] fp32 -> Wt [N][K] bf16 (one launch) ----------------
__global__ __launch_bounds__(256) void transpose_w4(const float* __restrict__ W0, const float* __restrict__ W1,
                                                    const float* __restrict__ W2, const float* __restrict__ W3,
                                                    u16* __restrict__ T0, u16* __restrict__ T1,
                                                    u16* __restrict__ T2, u16* __restrict__ T3) {
    __shared__ float tile[32][33];
    int z = blockIdx.z;
    const float* W = (z == 0) ? W0 : (z == 1) ? W1 : (z == 2) ? W2 : W3;
    u16* Wt = (z == 0) ? T0 : (z == 1) ? T1 : (z == 2) ? T2 : T3;
    int tx = threadIdx.x, ty = threadIdx.y;           // 32 x 8
    int k0 = blockIdx.y * 32, n0 = blockIdx.x * 32;
    #pragma unroll
    for (int j = 0; j < 32; j += 8)
        tile[ty + j][tx] = W[(size_t)(k0 + ty + j) * DM + n0 + tx];
    __syncthreads();
    #pragma unroll
    for (int j = 0; j < 32; j += 8)
        Wt[(size_t)(n0 + ty + j) * DM + k0 + tx] = f2bf(tile[tx][ty + j]);
}

// ---------------- 128xBN GEMM, BK=32, global_load_lds staging ----------------
// MODE 0 (NI=4): QKV fused (N=3072): Q/K RoPE fused; V head-major. MODE 1: fp32 out.
template<int MODE, int NI>   // BN = NI*32
__global__ __launch_bounds__(256) void gemm128(const u16* __restrict__ A, const u16* __restrict__ Bt,
                                               u16* __restrict__ Qh, u16* __restrict__ Kh,
                                               u16* __restrict__ Vh, float* __restrict__ Cf) {
    __shared__ u16 Al[128 * 32];
    __shared__ u16 Bl[NI * 32 * 32];
    const int K = DM;
    int tid = threadIdx.x;
    int wave = tid >> 6, lane = tid & 63, g = lane >> 4, ln = lane & 15;
    int wm = (wave >> 1) * 64, wn = (wave & 1) * (NI * 16);
    size_t mb0 = (size_t)blockIdx.y * 128, nb0 = (size_t)blockIdx.x * (NI * 32);

    f32x4 acc[4][NI];
    #pragma unroll
    for (int i = 0; i < 4; i++)
        #pragma unroll
        for (int j = 0; j < NI; j++)
            acc[i][j] = (f32x4){0.f, 0.f, 0.f, 0.f};

    const u16* Ag = A + (mb0 + wave * 32 + (lane >> 2)) * K + (lane & 3) * 8;
    u16* Alw = Al + wave * 1024;
    const u16* Bg;
    u16* Blw;
    if (NI == 4) {
        Bg = Bt + (nb0 + wave * 32 + (lane >> 2)) * K + (lane & 3) * 8;
        Blw = Bl + wave * 1024;
    } else {
        Bg = Bt + (nb0 + wave * 16 + (lane >> 2)) * K + (lane & 3) * 8;
        Blw = Bl + wave * 512;
    }

    for (int k0 = 0; k0 < K; k0 += 32) {
        __syncthreads();
        #pragma unroll
        for (int c = 0; c < 2; c++)
            load_lds16(Ag + (size_t)c * 16 * K + k0, Alw + c * 512);
        if (NI == 4) {
            #pragma unroll
            for (int c = 0; c < 2; c++)
                load_lds16(Bg + (size_t)c * 16 * K + k0, Blw + c * 512);
        } else {
            load_lds16(Bg + k0, Blw);
        }
        __syncthreads();
        short8 af[4], bf[NI];
        #pragma unroll
        for (int i = 0; i < 4; i++)
            af[i] = *(const short8*)&Al[(wm + i * 16 + ln) * 32 + g * 8];
        #pragma unroll
        for (int i = 0; i < NI; i++)
            bf[i] = *(const short8*)&Bl[(wn + i * 16 + ln) * 32 + g * 8];
        #pragma unroll
        for (int mi = 0; mi < 4; mi++)
            #pragma unroll
            for (int ni = 0; ni < NI; ni++)
                acc[mi][ni] = __builtin_amdgcn_mfma_f32_16x16x32_bf16(af[mi], bf[ni], acc[mi][ni], 0, 0, 0);
    }

    if (MODE == 1) {
        #pragma unroll
        for (int mi = 0; mi < 4; mi++)
            #pragma unroll
            for (int ni = 0; ni < NI; ni++)
                #pragma unroll
                for (int r = 0; r < 4; r++) {
                    int m = (int)mb0 + wm + mi * 16 + g * 4 + r;
                    int n = (int)nb0 + wn + ni * 16 + ln;
                    Cf[(size_t)m * DM + n] = acc[mi][ni][r];
                }
    } else {
        int nbase = (int)nb0 + wn;              // wave-uniform
        int which = nbase >> 10;
        int h = (nbase & (DM - 1)) >> 6;
        if (which < 2) {
            u16* dst = (which == 0) ? Qh : Kh;
            float inv0 = exp2f(-0.4152408746976557f * (float)ln);
            float inv1 = exp2f(-0.4152408746976557f * (float)(16 + ln));
            #pragma unroll
            for (int mi = 0; mi < 4; mi++) {
                #pragma unroll
                for (int r = 0; r < 4; r++) {
                    int m = (int)mb0 + wm + mi * 16 + g * 4 + r;
                    int b = m >> 11, s = m & (S_LEN - 1);
                    float fs = (float)s;
                    float sn0, cs0, sn1, cs1;
                    __sincosf(fs * inv0, &sn0, &cs0);
                    __sincosf(fs * inv1, &sn1, &cs1);
                    float a0 = acc[mi][0][r], a1 = acc[mi][1][r];
                    float a2 = acc[mi][2][r], a3 = acc[mi][3][r];
                    size_t base = ((size_t)(b * NH + h) * S_LEN + s) * HD;
                    dst[base + ln]      = f2bf(a0 * cs0 - a2 * sn0);
                    dst[base + 16 + ln] = f2bf(a1 * cs1 - a3 * sn1);
                    dst[base + 32 + ln] = f2bf(a0 * sn0 + a2 * cs0);
                    dst[base + 48 + ln] = f2bf(a1 * sn1 + a3 * cs1);
                }
            }
        } else {
            #pragma unroll
            for (int mi = 0; mi < 4; mi++) {
                #pragma unroll
                for (int r = 0; r < 4; r++) {
                    int m = (int)mb0 + wm + mi * 16 + g * 4 + r;
                    int b = m >> 11, s = m & (S_LEN - 1);
                    size_t base = ((size_t)(b * NH + h) * S_LEN + s) * HD;
                    #pragma unroll
                    for (int ni = 0; ni < 4; ni++)
                        Vh[base + ni * 16 + ln] = f2bf(acc[mi][ni][r]);
                }
            }
        }
    }
}

// ---------------- V transpose: [BH][S][HD] -> [BH][HD][S] ----------------
__global__ __launch_bounds__(256) void vtrans(const u16* __restrict__ Vh, u16* __restrict__ Vt) {
    __shared__ u16 t[64][70];
    int tid = threadIdx.x;
    int s0 = blockIdx.x * 64, bh = blockIdx.y;
    int r = tid >> 2, c = (tid & 3) * 8;
    const u16* src = Vh + ((size_t)bh * S_LEN + s0) * HD;
    *(short8*)&t[r][c]      = *(const short8*)(src + (size_t)r * HD + c);
    *(short8*)&t[r][c + 32] = *(const short8*)(src + (size_t)r * HD + c + 32);
    __syncthreads();
    u16* dst = Vt + ((size_t)bh * HD + r) * S_LEN + s0;
    short8 o0, o1;
    #pragma unroll
    for (int j = 0; j < 8; j++) {
        o0[j] = (short)t[c + j][r];
        o1[j] = (short)t[c + 32 + j][r];
    }
    *(short8*)(dst + c)      = o0;
    *(short8*)(dst + c + 32) = o1;
}

// ---------------- Flash attention: S^T formulation, in-register P, K-split=4 ----------------
// S^T = K*Q^T (MFMA operand swap) -> P^T C-layout == B-operand layout of 16x16x16 MFMA
// -> PV (O^T = V^T * P^T) consumes P directly from registers. No P LDS round-trip.
// K/V LDS: stride 64 + XOR swizzle (c ^= row&7) -> conflict-free staging & frag reads.
// Output O^T stored unnormalized to Op[bh][d][q]; reduce pass combines 4 splits.
__global__ __launch_bounds__(512, 8) void flash_kernel(const u16* __restrict__ Qh, const u16* __restrict__ Kh,
                                                       const u16* __restrict__ Vt, const float* __restrict__ amask,
                                                       u16* __restrict__ Op0, u16* __restrict__ Op1,
                                                       u16* __restrict__ Op2, u16* __restrict__ Op3,
                                                       float* __restrict__ L0, float* __restrict__ L1,
                                                       float* __restrict__ L2, float* __restrict__ L3) {
    __shared__ u16 Kl[64 * 64];
    __shared__ u16 Vl[64 * 64];
    __shared__ float Ml[64];
    int tid = threadIdx.x;
    int wave = tid >> 6, lane = tid & 63, g = lane >> 4, ln = lane & 15;
    int qblk = 15 - ((int)blockIdx.x >> 2);
    int sp = blockIdx.x & 3;
    int bh = blockIdx.y;
    int b = bh >> 4, h = bh & (NH - 1);
    int q0 = qblk * 128 + wave * 16;
    int qv = q0 + ln;
    const u16* Qb = Qh + (size_t)bh * (S_LEN * HD);
    const u16* Kb = Kh + (size_t)bh * (S_LEN * HD);
    const u16* Vb = Vt + (size_t)bh * (S_LEN * HD);
    const float* am = amask + b * S_LEN;

    short8 qa0 = *(const short8*)(Qb + (size_t)(q0 + ln) * HD + g * 8);
    short8 qa1 = *(const short8*)(Qb + (size_t)(q0 + ln) * HD + 32 + g * 8);

    f32x4 O[4];
    #pragma unroll
    for (int i = 0; i < 4; i++) O[i] = (f32x4){0.f, 0.f, 0.f, 0.f};
    float lsum = 0.f;
    const float SCL = 0.125f * 1.4426950408889634f;       // scale * log2(e)
    const float MSCL = -1.4426950408889634e9f;            // -1e9 * log2(e)

    int T = 2 * qblk + 2;
    // staging: 512 threads, each 1 K-b128 + 1 V-b128, XOR-swizzled stride-64 LDS
    int srow = tid >> 3, scid = tid & 7, s7 = srow & 7;
    u16* KlW = Kl + srow * 64 + ((scid ^ s7) * 8);
    u16* VlW = Vl + srow * 64 + ((scid ^ s7) * 8);
    const u16* KgP = Kb + (size_t)srow * HD + scid * 8;
    const u16* VgP = Vb + (size_t)srow * S_LEN + scid * 8;

    // loop-invariant swizzled offsets
    int l7 = ln & 7;
    int kc0 = (g ^ l7) * 8;                 // K frag cols 0..31
    int kc1 = ((4 + g) ^ l7) * 8;           // K frag cols 32..63
    int rbq = ln * 64;                      // row base within 16-row tile
    int vcoff[4];
    #pragma unroll
    for (int n0 = 0; n0 < 4; n0++)
        vcoff[n0] = (((n0 * 2 + (g >> 1)) ^ l7) * 8) + ((g & 1) * 4);

    for (int kt = sp; kt < T; kt += 4) {
        int kbase = kt * 64;
        __syncthreads();
        *(short8*)KlW = *(const short8*)(KgP + (size_t)kbase * HD);
        *(short8*)VlW = *(const short8*)(VgP + kbase);
        if (tid < 64) Ml[tid] = (1.0f - am[kbase + tid]) * MSCL;
        __syncthreads();

        bool needmask = (kbase + 63 > q0);
        u32 pk[4][2];

        // ---- S^T = K*Q^T, exp2, pack P^T into registers ----
        #pragma unroll
        for (int n0 = 0; n0 < 4; n0++) {
            const u16* kr = Kl + (n0 * 16) * 64 + rbq;
            short8 kb0 = *(const short8*)(kr + kc0);
            short8 kb1 = *(const short8*)(kr + kc1);
            f32x4 sv = (f32x4){0.f, 0.f, 0.f, 0.f};
            sv = __builtin_amdgcn_mfma_f32_16x16x32_bf16(kb0, qa0, sv, 0, 0, 0);
            sv = __builtin_amdgcn_mfma_f32_16x16x32_bf16(kb1, qa1, sv, 0, 0, 0);
            f32x4 mkv = *(f32x4*)&Ml[n0 * 16 + g * 4];
            int keyb = kbase + n0 * 16 + g * 4;
            float p[4];
            #pragma unroll
            for (int r = 0; r < 4; r++) {
                float s2 = sv[r] * SCL + mkv[r];
                if (needmask && (keyb + r > qv)) s2 = -1.0e9f;
                p[r] = exp2f(s2);
                lsum += p[r];
            }
            pk[n0][0] = (u32)f2bf(p[0]) | ((u32)f2bf(p[1]) << 16);
            pk[n0][1] = (u32)f2bf(p[2]) | ((u32)f2bf(p[3]) << 16);
        }

        // ---- O^T += V^T * P^T : P straight from registers, V^T b64 frags from LDS ----
        #pragma unroll
        for (int t = 0; t < 4; t++) {
            const u16* vr = Vl + (t * 16) * 64 + rbq;
            #pragma unroll
            for (int n0 = 0; n0 < 4; n0++) {
                s4v va = *(const s4v*)(vr + vcoff[n0]);
                union { u32 u[2]; s4v v; } pb;
                pb.u[0] = pk[n0][0];
                pb.u[1] = pk[n0][1];
                O[t] = MFMA_K16(va, pb.v, O[t]);
            }
        }
    }

    // ---- epilogue: lsum over all 4 g-groups (2 shuffles), store unnormalized O^T ----
    lsum += __shfl_xor(lsum, 16, 64);
    lsum += __shfl_xor(lsum, 32, 64);
    u16* Od = (sp == 0) ? Op0 : (sp == 1) ? Op1 : (sp == 2) ? Op2 : Op3;
    float* Ld = (sp == 0) ? L0 : (sp == 1) ? L1 : (sp == 2) ? L2 : L3;
    if (lane < 16) Ld[(size_t)bh * S_LEN + q0 + ln] = lsum;
    size_t obase = (size_t)bh * (HD * S_LEN) + q0 + ln;
    #pragma unroll
    for (int t = 0; t < 4; t++)
        #pragma unroll
        for (int r = 0; r < 4; r++)
            Od[obase + (size_t)(t * 16 + g * 4 + r) * S_LEN] = f2bf(O[t][r]);
}

// ---------------- Reduce: attn[b][q][h*64+d] = sum_sp Op[bh][d][q] / sum_sp L ----------------
__global__ __launch_bounds__(256) void flash_reduce(const u16* __restrict__ Op0, const u16* __restrict__ Op1,
                                                    const u16* __restrict__ Op2, const u16* __restrict__ Op3,
                                                    const float* __restrict__ L0, const float* __restrict__ L1,
                                                    const float* __restrict__ L2, const float* __restrict__ L3,
                                                    u16* __restrict__ attn) {
    __shared__ float t[64][65];
    int tid = threadIdx.x;
    int qt = blockIdx.x, bh = blockIdx.y;
    int b = bh >> 4, h = bh & (NH - 1);
    #pragma unroll
    for (int it = 0; it < 2; it++) {
        int idx = tid + it * 256;
        int d = idx >> 3, c = (idx & 7) * 8;
        size_t off = (size_t)bh * (HD * S_LEN) + (size_t)d * S_LEN + qt * 64 + c;
        short8 a0 = *(const short8*)(Op0 + off);
        short8 a1 = *(const short8*)(Op1 + off);
        short8 a2 = *(const short8*)(Op2 + off);
        short8 a3 = *(const short8*)(Op3 + off);
        #pragma unroll
        for (int j = 0; j < 8; j++)
            t[d][c + j] = bf2f((u16)a0[j]) + bf2f((u16)a1[j]) + bf2f((u16)a2[j]) + bf2f((u16)a3[j]);
    }
    __syncthreads();
    int qr = tid >> 2, dc = (tid & 3) * 16;
    int qg = qt * 64 + qr;
    size_t li = (size_t)bh * S_LEN + qg;
    float inv = 1.0f / (L0[li] + L1[li] + L2[li] + L3[li]);
    short8 o0, o1;
    #pragma unroll
    for (int j = 0; j < 8; j++) {
        o0[j] = (short)f2bf(t[dc + j][qr] * inv);
        o1[j] = (short)f2bf(t[dc + 8 + j][qr] * inv);
    }
    u16* dst = attn + ((size_t)b * S_LEN + qg) * DM + h * HD + dc;
    *(short8*)dst = o0;
    *(short8*)(dst + 8) = o1;
}

extern "C" void kernel_launch(void* const* d_in, const int* in_sizes, int n_in,
                              void* d_out, int out_size, void* d_ws, size_t ws_size,
                              hipStream_t stream) {
    const float* x     = (const float*)d_in[0];
    const float* amask = (const float*)d_in[1];
    const float* Wq    = (const float*)d_in[2];
    const float* Wk    = (const float*)d_in[3];
    const float* Wv    = (const float*)d_in[4];
    const float* Wo    = (const float*)d_in[5];
    float* out = (float*)d_out;
    char* ws = (char*)d_ws;

    // [0,8M):      x_bf (dead after gemm<0>) -> Op1
    // [8M,9.1M):   L0..L3 (overlaps Wqkv_t, which is dead after gemm<0>)
    // [8M,14.7M):  Wqkv_t
    // [14M,16.7M): Wo_t (alive to the end)
    // [16M,24M):   Qh   [24M,32M): Kh
    // [32M,40M):   Vt (dead after flash) -> attn_final
    // [40M,48M):   Vh (dead after vtrans) -> Op0
    // Op2/Op3 in d_out (16 MB fp32, only written by final gemm).
    u16* x_bf   = (u16*)(ws);
    u16* Op1    = (u16*)(ws);
    u16* Wqkv_t = (u16*)(ws + 8388608);
    float* L0   = (float*)(ws + 8388608);
    float* L1   = (float*)(ws + 8650752);
    float* L2   = (float*)(ws + 8912896);
    float* L3   = (float*)(ws + 9175040);
    u16* Wo_t   = (u16*)(ws + 14680064);
    u16* Qh     = (u16*)(ws + 16777216);
    u16* Kh     = (u16*)(ws + 25165824);
    u16* Vt     = (u16*)(ws + 33554432);
    u16* attnF  = (u16*)(ws + 33554432);           // over Vt, after flash
    u16* Vh     = (u16*)(ws + 41943040);
    u16* Op0    = (u16*)(ws + 41943040);           // over Vh, after vtrans
    u16* Op2    = (u16*)d_out;
    u16* Op3    = (u16*)d_out + 4194304;

    cvt_bf16<<<4096, 256, 0, stream>>>(x, x_bf, 2 * S_LEN * DM);

    transpose_w4<<<dim3(32, 32, 4), dim3(32, 8), 0, stream>>>(
        Wq, Wk, Wv, Wo, Wqkv_t, Wqkv_t + 1048576, Wqkv_t + 2097152, Wo_t);

    gemm128<0, 4><<<dim3(24, 32), 256, 0, stream>>>(x_bf, Wqkv_t, Qh, Kh, Vh, nullptr);

    vtrans<<<dim3(32, 2 * NH), 256, 0, stream>>>(Vh, Vt);

    flash_kernel<<<dim3(64, 2 * NH), 512, 0, stream>>>(Qh, Kh, Vt, amask,
                                                       Op0, Op1, Op2, Op3, L0, L1, L2, L3);

    flash_reduce<<<dim3(32, 2 * NH), 256, 0, stream>>>(Op0, Op1, Op2, Op3,
                                                       L0, L1, L2, L3, attnF);

    gemm128<1, 2><<<dim3(16, 32), 256, 0, stream>>>(attnF, Wo_t, nullptr, nullptr, nullptr, out);
}